// Round 15
// baseline (397.549 us; speedup 1.0000x reference)
//
#include <hip/hip_runtime.h>
#include <hip/hip_fp16.h>

#define N_PTS 2048
#define YSTR 2052
#define SINK_ITERS 8
static constexpr float NORM_C = -8.31776616671934f; // -log(4096)

typedef unsigned short u16;
typedef unsigned int u32;

__device__ __forceinline__ float2 h2f2(u32 uu) {
  union { u32 u; __half2 h; } x; x.u = uu;
  return __half22float2(x.h);
}
__device__ __forceinline__ u16 f2h(float f) {
  __half h = __float2half_rn(f);
  return *(u16*)&h;
}
__device__ __forceinline__ float RL(float x, int lane) {
  return __int_as_float(__builtin_amdgcn_readlane(__float_as_int(x), lane));
}

// ------ Fused GEMM: ms=A·B^T/8 (fp32), E=expm1(ms) (fp16), ET=E^T via LDS ------
// Ts stride 84 u16 (42 dwords): per-tx row step 4*42=168 = 8 mod 32 dwords ->
// transpose WRITE spreads over 4 banks (was 16-way conflict at stride 80:
// 1.05e7 SQ_LDS_BANK_CONFLICT in R14). Rows 8B-aligned -> uint2 reads.
__global__ __launch_bounds__(256) void gemm_exp(
    const float* __restrict__ feats,
    float* __restrict__ msOut, u16* __restrict__ E, u16* __restrict__ ET,
    float* __restrict__ Yv)
{
  __shared__ float As[64][65];
  __shared__ float Bs[64][65];
  __shared__ u16 Ts[64][84];
  int b = blockIdx.z;
  int i0 = blockIdx.x * 64, j0 = blockIdx.y * 64;
  int t = threadIdx.x;
  if (blockIdx.x == 0 && blockIdx.y == 0) {
    for (int i = t; i < N_PTS + 1; i += 256) Yv[b * YSTR + i] = 1.0f;
  }
  const float* Abase = feats + ((size_t)(2*b + 0) * N_PTS + i0) * 64;
  const float* Bbase = feats + ((size_t)(2*b + 1) * N_PTS + j0) * 64;
  for (int idx = t; idx < 4096; idx += 256) {
    int r = idx >> 6, c = idx & 63;
    As[r][c] = Abase[(size_t)r * 64 + c];
    Bs[r][c] = Bbase[(size_t)r * 64 + c];
  }
  __syncthreads();
  int tx = t & 15, ty = t >> 4;
  float acc[4][4] = {};
  for (int k = 0; k < 64; ++k) {
    float av[4], bv[4];
    #pragma unroll
    for (int d = 0; d < 4; ++d) { av[d] = As[ty*4+d][k]; bv[d] = Bs[tx*4+d][k]; }
    #pragma unroll
    for (int di = 0; di < 4; ++di)
      #pragma unroll
      for (int dj = 0; dj < 4; ++dj)
        acc[di][dj] = fmaf(av[di], bv[dj], acc[di][dj]);
  }
  #pragma unroll
  for (int di = 0; di < 4; ++di) {
    float4 m4; ushort4 e4;
    #pragma unroll
    for (int dj = 0; dj < 4; ++dj) {
      float val = acc[di][dj] * 0.125f;
      ((float*)&m4)[dj] = val;
      u16 eh = f2h(expm1f(val));
      ((u16*)&e4)[dj] = eh;
      Ts[tx*4+dj][ty*4+di] = eh;
    }
    size_t o = ((size_t)b * N_PTS + (i0 + ty*4 + di)) * N_PTS + (j0 + tx*4);
    *(float4*)(msOut + o) = m4;
    *(ushort4*)(E + o) = e4;
  }
  __syncthreads();
  for (int idx = t; idx < 1024; idx += 256) {
    int r = idx >> 4, seg = idx & 15;
    uint2 w = *(const uint2*)&Ts[r][seg*4];
    *(uint2*)(ET + ((size_t)b * N_PTS + (j0 + r)) * N_PTS + i0 + seg*4) = w;
  }
}

// ---------------- Sinkhorn: 1 row/wave, 1024 blocks (bit-exact per-row) ------
__global__ __launch_bounds__(512) void sink_half(
    const u16* __restrict__ M, const float* __restrict__ Yin, float* __restrict__ Yout,
    const float* __restrict__ binp, float dustnum)
{
  int g = blockIdx.x;        // 0..255, 8 rows each (1 per wave)
  int b = blockIdx.y;        // 0..3
  int t = threadIdx.x;
  int wv = t >> 6, l = t & 63;
  const float A = expf(binp[0]);
  const u16* Mb = M + (size_t)b * N_PTS * N_PTS;
  const float* Yi = Yin + b * YSTR;
  float* Yo = Yout + b * YSTR;
  float ybin = Yi[N_PTS];

  float yv[32];
  const float4* yp = (const float4*)(Yi + l * 32);
  #pragma unroll
  for (int k = 0; k < 8; ++k) {
    float4 f4 = yp[k];
    yv[k*4+0] = f4.x; yv[k*4+1] = f4.y; yv[k*4+2] = f4.z; yv[k*4+3] = f4.w;
  }

  int row = g * 8 + wv;
  const uint4* rp = (const uint4*)(Mb + (size_t)row * N_PTS + l * 32);
  uint4 qv[4];
  #pragma unroll
  for (int k = 0; k < 4; ++k) qv[k] = rp[k];

  float Sv = 0.0f;
  #pragma unroll
  for (int k = 0; k < 32; ++k) Sv += yv[k];
  #pragma unroll
  for (int off = 32; off; off >>= 1) Sv += __shfl_xor(Sv, off);

  float a = 0.0f;
  #pragma unroll
  for (int k = 0; k < 4; ++k) {
    uint4 q = qv[k];
    float2 f;
    f = h2f2(q.x); a = fmaf(f.x, yv[k*8+0], a); a = fmaf(f.y, yv[k*8+1], a);
    f = h2f2(q.y); a = fmaf(f.x, yv[k*8+2], a); a = fmaf(f.y, yv[k*8+3], a);
    f = h2f2(q.z); a = fmaf(f.x, yv[k*8+4], a); a = fmaf(f.y, yv[k*8+5], a);
    f = h2f2(q.w); a = fmaf(f.x, yv[k*8+6], a); a = fmaf(f.y, yv[k*8+7], a);
  }
  #pragma unroll
  for (int off = 32; off; off >>= 1) a += __shfl_xor(a, off);

  if (l == 0)
    Yo[row] = 1.0f / (a + Sv + A * ybin);
  if (g == 0 && t == 0)
    Yo[N_PTS] = dustnum / (A * (Sv + ybin));
}

__global__ void uv_kernel(const float* __restrict__ Yu, const float* __restrict__ Yv,
                          float* __restrict__ u, float* __restrict__ v) {
  int i = blockIdx.x * 256 + threadIdx.x;
  int b = blockIdx.y;
  if (i < N_PTS + 1) {
    u[b*YSTR + i] = NORM_C + logf(Yu[b*YSTR + i]);
    v[b*YSTR + i] = logf(Yv[b*YSTR + i]);
  }
}

// ---------------- matching argmaxes (fp32 ms) ----------------
// R15: float4 ms reads, v in registers (no LDS/sync). Lane l owns
// j in [l*32, l*32+32) ascending; same add operands and lowest-j tie
// semantics as before -> identical matches.
__global__ __launch_bounds__(256) void argmax_rows(
    const float* __restrict__ ms, const float* __restrict__ v, int* __restrict__ nn12)
{
  int b = blockIdx.y, t = threadIdx.x;
  int wv = t >> 6, l = t & 63;
  int row = blockIdx.x * 4 + wv;
  const float* vb = v + b * YSTR;
  float vv[32];
  const float4* vp = (const float4*)(vb + l * 32);
  #pragma unroll
  for (int k = 0; k < 8; ++k) {
    float4 f4 = vp[k];
    vv[k*4+0] = f4.x; vv[k*4+1] = f4.y; vv[k*4+2] = f4.z; vv[k*4+3] = f4.w;
  }
  const float4* rp4 = (const float4*)(ms + ((size_t)b * N_PTS + row) * N_PTS + l * 32);
  float best = -1e30f; int bj = 0;
  #pragma unroll
  for (int k = 0; k < 8; ++k) {
    float4 q = rp4[k];
    #pragma unroll
    for (int e = 0; e < 4; ++e) {
      float val = ((const float*)&q)[e] + vv[k*4 + e];
      int j = l*32 + k*4 + e;
      if (val > best) { best = val; bj = j; }
    }
  }
  for (int off = 32; off; off >>= 1) {
    float ov = __shfl_down(best, off);
    int oj = __shfl_down(bj, off);
    if (ov > best || (ov == best && oj < bj)) { best = ov; bj = oj; }
  }
  if (l == 0) nn12[b * N_PTS + row] = bj;
}

__global__ __launch_bounds__(256) void argmax_cols_part(
    const float* __restrict__ ms, const float* __restrict__ u,
    float* __restrict__ pbest, int* __restrict__ pidx)
{
  int b = blockIdx.y;
  int strip = blockIdx.x >> 3;      // 0..15
  int jb = blockIdx.x & 7;          // 0..7
  int j = jb * 256 + threadIdx.x;
  const float* mb = ms + (size_t)b * N_PTS * N_PTS;
  const float* ub = u + b * YSTR;
  float best = -1e30f; int bi = 0;
  int i0 = strip * 128;
  for (int i = i0; i < i0 + 128; ++i) {
    float val = mb[(size_t)i * N_PTS + j] + ub[i];
    if (val > best) { best = val; bi = i; }
  }
  pbest[((size_t)b * 16 + strip) * N_PTS + j] = best;
  pidx [((size_t)b * 16 + strip) * N_PTS + j] = bi;
}

__global__ void argmax_cols_merge(
    const float* __restrict__ pbest, const int* __restrict__ pidx, int* __restrict__ nn21)
{
  int b = blockIdx.y;
  int j = blockIdx.x * 256 + threadIdx.x;
  float best = -1e30f; int bi = 0;
  for (int s = 0; s < 16; ++s) {
    float v = pbest[((size_t)b * 16 + s) * N_PTS + j];
    int ii = pidx[((size_t)b * 16 + s) * N_PTS + j];
    if (v > best) { best = v; bi = ii; }
  }
  nn21[b * N_PTS + j] = bi;
}

// ---------------- MLP + x0/x1 (point x neuron parallel, 2048 blocks) ----
__device__ __forceinline__ void inv3(const float* a, float* o) {
  float d = a[0]*(a[4]*a[8]-a[5]*a[7]) - a[1]*(a[3]*a[8]-a[5]*a[6]) + a[2]*(a[3]*a[7]-a[4]*a[6]);
  float id = 1.0f / d;
  o[0]=(a[4]*a[8]-a[5]*a[7])*id; o[1]=(a[2]*a[7]-a[1]*a[8])*id; o[2]=(a[1]*a[5]-a[2]*a[4])*id;
  o[3]=(a[5]*a[6]-a[3]*a[8])*id; o[4]=(a[0]*a[8]-a[2]*a[6])*id; o[5]=(a[2]*a[3]-a[0]*a[5])*id;
  o[6]=(a[3]*a[7]-a[4]*a[6])*id; o[7]=(a[1]*a[6]-a[0]*a[7])*id; o[8]=(a[0]*a[4]-a[1]*a[3])*id;
}

__global__ __launch_bounds__(256) void mlp_kernel(
    const float* __restrict__ feats, const float* __restrict__ scores,
    const float* __restrict__ kpts, const float* __restrict__ Kmat,
    const float* __restrict__ ms, const float* __restrict__ u, const float* __restrict__ v,
    const int* __restrict__ nn12, const int* __restrict__ nn21,
    const float* __restrict__ W1, const float* __restrict__ b1,
    const float* __restrict__ W2, const float* __restrict__ b2,
    const float* __restrict__ W3, const float* __restrict__ b3,
    float* __restrict__ conf, float* __restrict__ x0a, float* __restrict__ x1a)
{
  __shared__ float sW1T[131*66];   // [c][o], stride 66
  __shared__ float sW2T[64*66];    // [c][o], stride 66
  __shared__ float sx[4][132];     // per-point inputs
  __shared__ float sh[4][64];      // h exchange
  int t = threadIdx.x, b = blockIdx.y;
  int p = t >> 6;                  // 0..3
  int o = t & 63;                  // 0..63
  int n = blockIdx.x * 4 + p;

  for (int i = t; i < 64*131; i += 256) { int oo = i / 131, c = i - oo * 131; sW1T[c*66 + oo] = W1[i]; }
  for (int i = t; i < 64*64;  i += 256) { int oo = i >> 6, c = i & 63; sW2T[c*66 + oo] = W2[i]; }

  int nn = nn21[b * N_PTS + n];
  bool mutual = (nn12[b * N_PTS + nn] == n);
  int m = mutual ? nn : 0;
  float vf = mutual ? 1.0f : 0.0f;
  const float* f0r = feats + ((size_t)(2*b) * N_PTS + n) * 64;
  const float* f1r = feats + ((size_t)(2*b+1) * N_PTS + m) * 64;
  sx[p][o]      = f0r[o];
  sx[p][64 + o] = vf * f1r[o];
  if (o == 0) {
    sx[p][128] = scores[(size_t)(2*b) * N_PTS + n];
    sx[p][129] = vf * scores[(size_t)(2*b+1) * N_PTS + m];
    sx[p][130] = vf * (ms[((size_t)b * N_PTS + n) * N_PTS + m] + u[b*YSTR + n] + v[b*YSTR + m] - NORM_C);
  }
  __syncthreads();

  float h = b1[o];
  for (int c = 0; c < 131; ++c) h = fmaf(sW1T[c*66 + o], sx[p][c], h);
  sh[p][o] = fmaxf(h, 0.0f);
  __syncthreads();

  float h2 = b2[o];
  for (int c = 0; c < 64; ++c) h2 = fmaf(sW2T[c*66 + o], sh[p][c], h2);
  __syncthreads();
  sh[p][o] = fmaxf(h2, 0.0f);
  __syncthreads();

  if (o == 0) {
    float z = b3[0];
    for (int c = 0; c < 64; ++c) z = fmaf(W3[c], sh[p][c], z);
    conf[b * N_PTS + n] = vf / (1.0f + expf(-z));
  }

  if (o < 3) {
    float K0[9], K1[9], K0i[9], K1i[9];
    #pragma unroll
    for (int i = 0; i < 9; ++i) { K0[i] = Kmat[(size_t)(b*2+0)*9 + i]; K1[i] = Kmat[(size_t)(b*2+1)*9 + i]; }
    inv3(K0, K0i); inv3(K1, K1i);
    float kx0 = kpts[((size_t)(2*b) * N_PTS + n)*2 + 0], ky0 = kpts[((size_t)(2*b) * N_PTS + n)*2 + 1];
    float kx1 = vf * kpts[((size_t)(2*b+1) * N_PTS + m)*2 + 0], ky1 = vf * kpts[((size_t)(2*b+1) * N_PTS + m)*2 + 1];
    x0a[((size_t)b * N_PTS + n)*3 + o] = K0i[o*3+0]*kx0 + K0i[o*3+1]*ky0 + K0i[o*3+2];
    x1a[((size_t)b * N_PTS + n)*3 + o] = K1i[o*3+0]*kx1 + K1i[o*3+1]*ky1 + K1i[o*3+2];
  }
}

// ---------------- M9 accumulation ----------------
__global__ __launch_bounds__(256) void m9_kernel(
    const float* __restrict__ conf, const float* __restrict__ x0a, const float* __restrict__ x1a,
    float* __restrict__ M9)
{
  __shared__ float part[4][45];
  int b = blockIdx.x, t = threadIdx.x;
  int wv = t >> 6, l = t & 63;
  float acc[45];
  #pragma unroll
  for (int e = 0; e < 45; ++e) acc[e] = 0.0f;
  for (int n = t; n < N_PTS; n += 256) {
    float w = conf[b * N_PTS + n];
    float X0[3], X1[3];
    #pragma unroll
    for (int i = 0; i < 3; ++i) { X0[i] = x0a[((size_t)b*N_PTS+n)*3+i]; X1[i] = x1a[((size_t)b*N_PTS+n)*3+i]; }
    float a9[9];
    #pragma unroll
    for (int i = 0; i < 3; ++i)
      #pragma unroll
      for (int j = 0; j < 3; ++j) a9[3*i+j] = X1[i] * X0[j];
    int idx = 0;
    #pragma unroll
    for (int p = 0; p < 9; ++p)
      #pragma unroll
      for (int q = p; q < 9; ++q) { acc[idx] = fmaf(w * a9[p], a9[q], acc[idx]); ++idx; }
  }
  #pragma unroll
  for (int e = 0; e < 45; ++e) {
    float s = acc[e];
    for (int off = 32; off; off >>= 1) s += __shfl_down(s, off);
    if (l == 0) part[wv][e] = s;
  }
  __syncthreads();
  if (t < 45) M9[b*45 + t] = part[0][t] + part[1][t] + part[2][t] + part[3][t];
}

// ---------------- pose: eigen (readlane + skip; 8 sweeps) ----------------
template<int NN>
__device__ void jacobi_reg(float* A, float* V, int sweeps) {
  #pragma unroll
  for (int i = 0; i < NN*NN; ++i) V[i] = 0.0f;
  #pragma unroll
  for (int i = 0; i < NN; ++i) V[i*NN+i] = 1.0f;
  for (int s = 0; s < sweeps; ++s) {
    #pragma unroll
    for (int p = 0; p < NN-1; ++p) {
      #pragma unroll
      for (int q = p+1; q < NN; ++q) {
        float apq = A[p*NN+q];
        if (fabsf(apq) > 1e-30f) {
          float app = A[p*NN+p], aqq = A[q*NN+q];
          float tau = (aqq - app) / (2.0f * apq);
          float tt = (tau >= 0.0f ? 1.0f : -1.0f) / (fabsf(tau) + sqrtf(1.0f + tau*tau));
          float c = 1.0f / sqrtf(1.0f + tt*tt);
          float sn = tt * c;
          #pragma unroll
          for (int k = 0; k < NN; ++k) {
            float akp = A[k*NN+p], akq = A[k*NN+q];
            A[k*NN+p] = c*akp - sn*akq;
            A[k*NN+q] = sn*akp + c*akq;
          }
          #pragma unroll
          for (int k = 0; k < NN; ++k) {
            float apk = A[p*NN+k], aqk = A[q*NN+k];
            A[p*NN+k] = c*apk - sn*aqk;
            A[q*NN+k] = sn*apk + c*aqk;
          }
          #pragma unroll
          for (int k = 0; k < NN; ++k) {
            float vkp = V[k*NN+p], vkq = V[k*NN+q];
            V[k*NN+p] = c*vkp - sn*vkq;
            V[k*NN+q] = sn*vkp + c*vkq;
          }
        }
      }
    }
  }
}

__device__ __forceinline__ void cross3(const float* a, const float* b, float* o) {
  o[0] = a[1]*b[2] - a[2]*b[1];
  o[1] = a[2]*b[0] - a[0]*b[2];
  o[2] = a[0]*b[1] - a[1]*b[0];
}
__device__ __forceinline__ float dot3(const float* a, const float* b) {
  return a[0]*b[0] + a[1]*b[1] + a[2]*b[2];
}

__global__ __launch_bounds__(64, 1) void eigen_kernel(
    const float* __restrict__ M9, float* __restrict__ cndg)
{
  int b = blockIdx.x;
  int l = threadIdx.x;
  float Ar[9], Vr[9];
  #pragma unroll
  for (int c = 0; c < 9; ++c) { Ar[c] = 0.0f; Vr[c] = 0.0f; }
  if (l < 9) {
    #pragma unroll
    for (int c = 0; c < 9; ++c) {
      int p = l < c ? l : c, q = l < c ? c : l;
      int idx = p * 9 - (p * (p - 1)) / 2 + (q - p);
      Ar[c] = M9[b * 45 + idx];
    }
    #pragma unroll
    for (int c = 0; c < 9; ++c) Vr[c] = (c == l) ? 1.0f : 0.0f;
  }

  for (int s = 0; s < 8; ++s) {
    #pragma unroll
    for (int p = 0; p < 8; ++p) {
      #pragma unroll
      for (int q = p + 1; q < 9; ++q) {
        float app = RL(Ar[p], p);
        float apq = RL(Ar[q], p);
        float aqq = RL(Ar[q], q);
        float thr = 3e-7f * (fabsf(app) + fabsf(aqq));
        if (fabsf(apq) > 1e-30f && fabsf(apq) > thr) {   // uniform branch
          float gp[9], gq[9];
          #pragma unroll
          for (int k = 0; k < 9; ++k) { gp[k] = RL(Ar[k], p); gq[k] = RL(Ar[k], q); }
          float tau = (aqq - app) / (2.0f * apq);
          float tt = (tau >= 0.0f ? 1.0f : -1.0f) / (fabsf(tau) + sqrtf(1.0f + tau*tau));
          float cc = 1.0f / sqrtf(1.0f + tt*tt);
          float sn = tt * cc;
          float akp = Ar[p], akq = Ar[q];
          Ar[p] = cc*akp - sn*akq;
          Ar[q] = sn*akp + cc*akq;
          float pp = RL(Ar[p], p), pq = RL(Ar[q], p);
          float qp = RL(Ar[p], q), qq = RL(Ar[q], q);
          if (l == p) {
            #pragma unroll
            for (int k = 0; k < 9; ++k) {
              float rp_ = (k==p) ? pp : ((k==q) ? pq : gp[k]);
              float rq_ = (k==p) ? qp : ((k==q) ? qq : gq[k]);
              Ar[k] = cc*rp_ - sn*rq_;
            }
          } else if (l == q) {
            #pragma unroll
            for (int k = 0; k < 9; ++k) {
              float rp_ = (k==p) ? pp : ((k==q) ? pq : gp[k]);
              float rq_ = (k==p) ? qp : ((k==q) ? qq : gq[k]);
              Ar[k] = sn*rp_ + cc*rq_;
            }
          }
          float vkp = Vr[p], vkq = Vr[q];
          Vr[p] = cc*vkp - sn*vkq;
          Vr[q] = sn*vkp + cc*vkq;
        }
      }
    }
  }

  float dl = Ar[0];
  #pragma unroll
  for (int i = 1; i < 9; ++i) dl = (l == i) ? Ar[i] : dl;
  int mi = 0;
  float mv = RL(dl, 0);
  #pragma unroll
  for (int i = 1; i < 9; ++i) {
    float d = RL(dl, i);
    if (d < mv) { mv = d; mi = i; }
  }
  float vmi = Vr[0];
  #pragma unroll
  for (int i = 1; i < 9; ++i) vmi = (i == mi) ? Vr[i] : vmi;
  float Em[9];
  #pragma unroll
  for (int k = 0; k < 9; ++k) Em[k] = __shfl(vmi, k);

  if (l != 0) return;

  float B3[9], V3[9];
  #pragma unroll
  for (int i = 0; i < 3; ++i)
    #pragma unroll
    for (int j = 0; j < 3; ++j) {
      float s = 0.0f;
      #pragma unroll
      for (int r = 0; r < 3; ++r) s += Em[3*r+i] * Em[3*r+j];
      B3[i*3+j] = s;
    }
  jacobi_reg<3>(B3, V3, 10);
  float l0 = B3[0], l1 = B3[4], l2 = B3[8];
  float va[3] = {V3[0], V3[3], V3[6]};
  float vb[3] = {V3[1], V3[4], V3[7]};
  float vc[3] = {V3[2], V3[5], V3[8]};
  #define SWF(x,y) { float _t = x; x = y; y = _t; }
  #define SW3(x,y) { SWF(x[0],y[0]) SWF(x[1],y[1]) SWF(x[2],y[2]) }
  if (l0 < l1) { SWF(l0,l1) SW3(va,vb) }
  if (l0 < l2) { SWF(l0,l2) SW3(va,vc) }
  if (l1 < l2) { SWF(l1,l2) SW3(vb,vc) }
  float s0 = sqrtf(fmaxf(l0, 0.0f)) + 1e-20f;
  float s1 = sqrtf(fmaxf(l1, 0.0f)) + 1e-20f;
  float u0[3], u1[3], u2[3], Ev2[3];
  #pragma unroll
  for (int r = 0; r < 3; ++r) {
    u0[r]  = (Em[3*r]*va[0] + Em[3*r+1]*va[1] + Em[3*r+2]*va[2]) / s0;
    u1[r]  = (Em[3*r]*vb[0] + Em[3*r+1]*vb[1] + Em[3*r+2]*vb[2]) / s1;
    Ev2[r] =  Em[3*r]*vc[0] + Em[3*r+1]*vc[1] + Em[3*r+2]*vc[2];
  }
  cross3(u0, u1, u2);
  if (dot3(Ev2, u2) < 0.0f) { u2[0] = -u2[0]; u2[1] = -u2[1]; u2[2] = -u2[2]; }
  float c12[3]; cross3(u1, u2, c12);
  float detU = dot3(u0, c12);
  if (detU < 0.0f)
    #pragma unroll
    for (int i = 0; i < 3; ++i) { u0[i] = -u0[i]; u1[i] = -u1[i]; u2[i] = -u2[i]; }
  float cv[3]; cross3(vb, vc, cv);
  float detV = dot3(va, cv);
  if (detV < 0.0f)
    #pragma unroll
    for (int i = 0; i < 3; ++i) { va[i] = -va[i]; vb[i] = -vb[i]; vc[i] = -vc[i]; }
  float* C = cndg + b * 48;
  #pragma unroll
  for (int r = 0; r < 3; ++r)
    #pragma unroll
    for (int c = 0; c < 3; ++c) {
      float r1 =  u1[r]*va[c] - u0[r]*vb[c] + u2[r]*vc[c];
      float r2 = -u1[r]*va[c] + u0[r]*vb[c] + u2[r]*vc[c];
      C[0*12 + r*3+c] = r1; C[1*12 + r*3+c] = r1;
      C[2*12 + r*3+c] = r2; C[3*12 + r*3+c] = r2;
    }
  #pragma unroll
  for (int i = 0; i < 3; ++i) {
    C[0*12 + 9+i] = u2[i]; C[1*12 + 9+i] = -u2[i];
    C[2*12 + 9+i] = u2[i]; C[3*12 + 9+i] = -u2[i];
  }
}

// ---------------- pose: cheirality + output ----------------
__global__ __launch_bounds__(256) void cheir_kernel(
    const float* __restrict__ cndg, const float* __restrict__ conf,
    const float* __restrict__ x0a, const float* __restrict__ x1a,
    const float* __restrict__ t_scale, float* __restrict__ out)
{
  __shared__ float cnd[4][12];
  __shared__ float spart[4][4];
  int b = blockIdx.x, t = threadIdx.x;
  if (t < 48) cnd[t / 12][t % 12] = cndg[b * 48 + t];
  __syncthreads();
  float ls[4] = {0,0,0,0};
  for (int n = t; n < N_PTS; n += 256) {
    float w = conf[b * N_PTS + n];
    float X0[3], X1[3];
    #pragma unroll
    for (int i = 0; i < 3; ++i) { X0[i] = x0a[((size_t)b*N_PTS+n)*3+i]; X1[i] = x1a[((size_t)b*N_PTS+n)*3+i]; }
    #pragma unroll
    for (int k = 0; k < 4; ++k) {
      float rx = cnd[k][0]*X0[0] + cnd[k][1]*X0[1] + cnd[k][2]*X0[2];
      float ry = cnd[k][3]*X0[0] + cnd[k][4]*X0[1] + cnd[k][5]*X0[2];
      float rz = cnd[k][6]*X0[0] + cnd[k][7]*X0[1] + cnd[k][8]*X0[2];
      float tx = cnd[k][9], ty = cnd[k][10], tz = cnd[k][11];
      float cx = X1[1]*rz - X1[2]*ry;
      float cy = X1[2]*rx - X1[0]*rz;
      float cz = X1[0]*ry - X1[1]*rx;
      float ctx = X1[1]*tz - X1[2]*ty;
      float cty = X1[2]*tx - X1[0]*tz;
      float ctz = X1[0]*ty - X1[1]*tx;
      float num = ctx*cx + cty*cy + ctz*cz;
      float den = cx*cx + cy*cy + cz*cz + 1e-9f;
      float d0 = -num / den;
      float d1 = d0 * rz + tz;
      if (d0 > 0.0f && d1 > 0.0f) ls[k] += w;
    }
  }
  int wv = t >> 6, l = t & 63;
  #pragma unroll
  for (int k = 0; k < 4; ++k) {
    float s = ls[k];
    for (int off = 32; off; off >>= 1) s += __shfl_down(s, off);
    if (l == 0) spart[wv][k] = s;
  }
  __syncthreads();
  if (t == 0) {
    float sc[4];
    #pragma unroll
    for (int k = 0; k < 4; ++k) sc[k] = spart[0][k] + spart[1][k] + spart[2][k] + spart[3][k];
    int best = 0;
    #pragma unroll
    for (int k = 1; k < 4; ++k) if (sc[k] > sc[best]) best = k;
    float R[9], tv[3];
    #pragma unroll
    for (int i = 0; i < 9; ++i) R[i] = cnd[best][i];
    #pragma unroll
    for (int i = 0; i < 3; ++i) tv[i] = cnd[best][9+i];
    float tn = sqrtf(tv[0]*tv[0] + tv[1]*tv[1] + tv[2]*tv[2]) + 1e-9f;
    float scl = t_scale[b] / tn;
    float tb[3] = {tv[0]*scl, tv[1]*scl, tv[2]*scl};
    float* o = out + b * 32;
    #pragma unroll
    for (int r = 0; r < 3; ++r) {
      o[r*4+0] = R[r*3+0]; o[r*4+1] = R[r*3+1]; o[r*4+2] = R[r*3+2]; o[r*4+3] = tb[r];
    }
    o[12] = 0; o[13] = 0; o[14] = 0; o[15] = 1;
    float* oi = o + 16;
    #pragma unroll
    for (int r = 0; r < 3; ++r) {
      oi[r*4+0] = R[0*3+r]; oi[r*4+1] = R[1*3+r]; oi[r*4+2] = R[2*3+r];
      oi[r*4+3] = -(R[0*3+r]*tb[0] + R[1*3+r]*tb[1] + R[2*3+r]*tb[2]);
    }
    oi[12] = 0; oi[13] = 0; oi[14] = 0; oi[15] = 1;
  }
}

// ---------------- host ----------------
extern "C" void kernel_launch(void* const* d_in, const int* in_sizes, int n_in,
                              void* d_out, int out_size, void* d_ws, size_t ws_size,
                              hipStream_t stream) {
  (void)in_sizes; (void)n_in; (void)out_size;
  const float* feats   = (const float*)d_in[0];
  const float* scores  = (const float*)d_in[1];
  const float* kpts    = (const float*)d_in[2];
  const float* t_scale = (const float*)d_in[3];
  const float* Kmat    = (const float*)d_in[4];
  const float* binp    = (const float*)d_in[6];
  const float* W1 = (const float*)d_in[7];
  const float* b1 = (const float*)d_in[8];
  const float* W2 = (const float*)d_in[9];
  const float* b2 = (const float*)d_in[10];
  const float* W3 = (const float*)d_in[11];
  const float* b3 = (const float*)d_in[12];
  float* out = (float*)d_out;

  const size_t NELEM = (size_t)4 * N_PTS * N_PTS;   // 16,777,216
  char* w = (char*)d_ws;
  float* ms = (float*)w;          w += NELEM * 4;
  u16*   E  = (u16*)w;            w += NELEM * 2;
  u16*   ET = (u16*)w;            w += NELEM * 2;
  float* Yu = (float*)w;          w += (size_t)4 * YSTR * 4;
  float* Yv = (float*)w;          w += (size_t)4 * YSTR * 4;
  float* uA = (float*)w;          w += (size_t)4 * YSTR * 4;
  float* vA = (float*)w;          w += (size_t)4 * YSTR * 4;
  int* nn12 = (int*)w;            w += (size_t)4 * N_PTS * 4;
  int* nn21 = (int*)w;            w += (size_t)4 * N_PTS * 4;
  float* conf = (float*)w;        w += (size_t)4 * N_PTS * 4;
  float* x0a  = (float*)w;        w += (size_t)4 * N_PTS * 3 * 4;
  float* x1a  = (float*)w;        w += (size_t)4 * N_PTS * 3 * 4;
  float* M9   = (float*)w;        w += (size_t)4 * 45 * 4;
  float* cndg = (float*)w;        w += (size_t)4 * 48 * 4;
  float* pbest = (float*)w;       w += (size_t)4 * 16 * N_PTS * 4;
  int*   pidx  = (int*)w;         w += (size_t)4 * 16 * N_PTS * 4;
  if ((size_t)(w - (char*)d_ws) > ws_size) return;

  gemm_exp<<<dim3(32,32,4), 256, 0, stream>>>(feats, ms, E, ET, Yv);
  for (int it = 0; it < SINK_ITERS; ++it) {
    sink_half<<<dim3(256,4), 512, 0, stream>>>(E,  Yv, Yu, binp, 2048.0f);
    sink_half<<<dim3(256,4), 512, 0, stream>>>(ET, Yu, Yv, binp, 2048.0f);
  }
  uv_kernel<<<dim3(9,4), 256, 0, stream>>>(Yu, Yv, uA, vA);
  argmax_rows<<<dim3(512,4), 256, 0, stream>>>(ms, vA, nn12);
  argmax_cols_part<<<dim3(128,4), 256, 0, stream>>>(ms, uA, pbest, pidx);
  argmax_cols_merge<<<dim3(8,4), 256, 0, stream>>>(pbest, pidx, nn21);
  mlp_kernel<<<dim3(512,4), 256, 0, stream>>>(feats, scores, kpts, Kmat, ms, uA, vA,
                                              nn12, nn21, W1, b1, W2, b2, W3, b3,
                                              conf, x0a, x1a);
  m9_kernel<<<4, 256, 0, stream>>>(conf, x0a, x1a, M9);
  eigen_kernel<<<4, 64, 0, stream>>>(M9, cndg);
  cheir_kernel<<<4, 256, 0, stream>>>(cndg, conf, x0a, x1a, t_scale, out);
}

// Round 16
// 345.307 us; speedup vs baseline: 1.1513x; 1.1513x over previous
//
#include <hip/hip_runtime.h>
#include <hip/hip_fp16.h>

#define N_PTS 2048
#define YSTR 2052
#define SINK_ITERS 8
static constexpr float NORM_C = -8.31776616671934f; // -log(4096)

typedef unsigned short u16;
typedef unsigned int u32;

__device__ __forceinline__ float2 h2f2(u32 uu) {
  union { u32 u; __half2 h; } x; x.u = uu;
  return __half22float2(x.h);
}
__device__ __forceinline__ u16 f2h(float f) {
  __half h = __float2half_rn(f);
  return *(u16*)&h;
}
__device__ __forceinline__ float RL(float x, int lane) {
  return __int_as_float(__builtin_amdgcn_readlane(__float_as_int(x), lane));
}

// ------ Fused GEMM: ms=A·B^T/8 (fp32), E=expm1(ms) (fp16), ET=E^T via LDS ------
// Ts stride 84 u16: transpose write spreads over 4 banks (R15-verified gain);
// rows 8B-aligned -> uint2 reads.
__global__ __launch_bounds__(256) void gemm_exp(
    const float* __restrict__ feats,
    float* __restrict__ msOut, u16* __restrict__ E, u16* __restrict__ ET,
    float* __restrict__ Yv)
{
  __shared__ float As[64][65];
  __shared__ float Bs[64][65];
  __shared__ u16 Ts[64][84];
  int b = blockIdx.z;
  int i0 = blockIdx.x * 64, j0 = blockIdx.y * 64;
  int t = threadIdx.x;
  if (blockIdx.x == 0 && blockIdx.y == 0) {
    for (int i = t; i < N_PTS + 1; i += 256) Yv[b * YSTR + i] = 1.0f;
  }
  const float* Abase = feats + ((size_t)(2*b + 0) * N_PTS + i0) * 64;
  const float* Bbase = feats + ((size_t)(2*b + 1) * N_PTS + j0) * 64;
  for (int idx = t; idx < 4096; idx += 256) {
    int r = idx >> 6, c = idx & 63;
    As[r][c] = Abase[(size_t)r * 64 + c];
    Bs[r][c] = Bbase[(size_t)r * 64 + c];
  }
  __syncthreads();
  int tx = t & 15, ty = t >> 4;
  float acc[4][4] = {};
  for (int k = 0; k < 64; ++k) {
    float av[4], bv[4];
    #pragma unroll
    for (int d = 0; d < 4; ++d) { av[d] = As[ty*4+d][k]; bv[d] = Bs[tx*4+d][k]; }
    #pragma unroll
    for (int di = 0; di < 4; ++di)
      #pragma unroll
      for (int dj = 0; dj < 4; ++dj)
        acc[di][dj] = fmaf(av[di], bv[dj], acc[di][dj]);
  }
  #pragma unroll
  for (int di = 0; di < 4; ++di) {
    float4 m4; ushort4 e4;
    #pragma unroll
    for (int dj = 0; dj < 4; ++dj) {
      float val = acc[di][dj] * 0.125f;
      ((float*)&m4)[dj] = val;
      u16 eh = f2h(expm1f(val));
      ((u16*)&e4)[dj] = eh;
      Ts[tx*4+dj][ty*4+di] = eh;
    }
    size_t o = ((size_t)b * N_PTS + (i0 + ty*4 + di)) * N_PTS + (j0 + tx*4);
    *(float4*)(msOut + o) = m4;
    *(ushort4*)(E + o) = e4;
  }
  __syncthreads();
  for (int idx = t; idx < 1024; idx += 256) {
    int r = idx >> 4, seg = idx & 15;
    uint2 w = *(const uint2*)&Ts[r][seg*4];
    *(uint2*)(ET + ((size_t)b * N_PTS + (j0 + r)) * N_PTS + i0 + seg*4) = w;
  }
}

// ---------------- Sinkhorn (R13/R14-proven: 2 rows/wave, grid 128x4) --------
__global__ __launch_bounds__(512) void sink_half(
    const u16* __restrict__ M, const float* __restrict__ Yin, float* __restrict__ Yout,
    const float* __restrict__ binp, float dustnum)
{
  int g = blockIdx.x;        // 0..127, 16 rows each
  int b = blockIdx.y;        // 0..3
  int t = threadIdx.x;
  int wv = t >> 6, l = t & 63;
  const float A = expf(binp[0]);
  const u16* Mb = M + (size_t)b * N_PTS * N_PTS;
  const float* Yi = Yin + b * YSTR;
  float* Yo = Yout + b * YSTR;
  float ybin = Yi[N_PTS];

  float yv[32];
  const float4* yp = (const float4*)(Yi + l * 32);
  #pragma unroll
  for (int k = 0; k < 8; ++k) {
    float4 f4 = yp[k];
    yv[k*4+0] = f4.x; yv[k*4+1] = f4.y; yv[k*4+2] = f4.z; yv[k*4+3] = f4.w;
  }

  int row0 = g * 16 + wv * 2;
  uint4 qv[2][4];
  #pragma unroll
  for (int r = 0; r < 2; ++r) {
    const uint4* rp = (const uint4*)(Mb + (size_t)(row0 + r) * N_PTS + l * 32);
    #pragma unroll
    for (int k = 0; k < 4; ++k) qv[r][k] = rp[k];
  }

  float Sv = 0.0f;
  #pragma unroll
  for (int k = 0; k < 32; ++k) Sv += yv[k];
  #pragma unroll
  for (int off = 32; off; off >>= 1) Sv += __shfl_xor(Sv, off);

  float acc[2];
  #pragma unroll
  for (int r = 0; r < 2; ++r) {
    float a = 0.0f;
    #pragma unroll
    for (int k = 0; k < 4; ++k) {
      uint4 q = qv[r][k];
      float2 f;
      f = h2f2(q.x); a = fmaf(f.x, yv[k*8+0], a); a = fmaf(f.y, yv[k*8+1], a);
      f = h2f2(q.y); a = fmaf(f.x, yv[k*8+2], a); a = fmaf(f.y, yv[k*8+3], a);
      f = h2f2(q.z); a = fmaf(f.x, yv[k*8+4], a); a = fmaf(f.y, yv[k*8+5], a);
      f = h2f2(q.w); a = fmaf(f.x, yv[k*8+6], a); a = fmaf(f.y, yv[k*8+7], a);
    }
    acc[r] = a;
  }
  #pragma unroll
  for (int r = 0; r < 2; ++r)
    #pragma unroll
    for (int off = 32; off; off >>= 1) acc[r] += __shfl_xor(acc[r], off);

  if (l == 0) {
    #pragma unroll
    for (int r = 0; r < 2; ++r)
      Yo[row0 + r] = 1.0f / (acc[r] + Sv + A * ybin);
  }
  if (g == 0 && t == 0)
    Yo[N_PTS] = dustnum / (A * (Sv + ybin));
}

__global__ void uv_kernel(const float* __restrict__ Yu, const float* __restrict__ Yv,
                          float* __restrict__ u, float* __restrict__ v) {
  int i = blockIdx.x * 256 + threadIdx.x;
  int b = blockIdx.y;
  if (i < N_PTS + 1) {
    u[b*YSTR + i] = NORM_C + logf(Yu[b*YSTR + i]);
    v[b*YSTR + i] = logf(Yv[b*YSTR + i]);
  }
}

// ---------------- matching argmaxes (fp32 ms) ----------------
__global__ __launch_bounds__(256) void argmax_rows(
    const float* __restrict__ ms, const float* __restrict__ v, int* __restrict__ nn12)
{
  int b = blockIdx.y, t = threadIdx.x;
  int wv = t >> 6, l = t & 63;
  int row = blockIdx.x * 4 + wv;
  const float* vb = v + b * YSTR;
  float vv[32];
  const float4* vp = (const float4*)(vb + l * 32);
  #pragma unroll
  for (int k = 0; k < 8; ++k) {
    float4 f4 = vp[k];
    vv[k*4+0] = f4.x; vv[k*4+1] = f4.y; vv[k*4+2] = f4.z; vv[k*4+3] = f4.w;
  }
  const float4* rp4 = (const float4*)(ms + ((size_t)b * N_PTS + row) * N_PTS + l * 32);
  float best = -1e30f; int bj = 0;
  #pragma unroll
  for (int k = 0; k < 8; ++k) {
    float4 q = rp4[k];
    #pragma unroll
    for (int e = 0; e < 4; ++e) {
      float val = ((const float*)&q)[e] + vv[k*4 + e];
      int j = l*32 + k*4 + e;
      if (val > best) { best = val; bj = j; }
    }
  }
  for (int off = 32; off; off >>= 1) {
    float ov = __shfl_down(best, off);
    int oj = __shfl_down(bj, off);
    if (ov > best || (ov == best && oj < bj)) { best = ov; bj = oj; }
  }
  if (l == 0) nn12[b * N_PTS + row] = bj;
}

__global__ __launch_bounds__(256) void argmax_cols_part(
    const float* __restrict__ ms, const float* __restrict__ u,
    float* __restrict__ pbest, int* __restrict__ pidx)
{
  int b = blockIdx.y;
  int strip = blockIdx.x >> 3;      // 0..15
  int jb = blockIdx.x & 7;          // 0..7
  int j = jb * 256 + threadIdx.x;
  const float* mb = ms + (size_t)b * N_PTS * N_PTS;
  const float* ub = u + b * YSTR;
  float best = -1e30f; int bi = 0;
  int i0 = strip * 128;
  for (int i = i0; i < i0 + 128; ++i) {
    float val = mb[(size_t)i * N_PTS + j] + ub[i];
    if (val > best) { best = val; bi = i; }
  }
  pbest[((size_t)b * 16 + strip) * N_PTS + j] = best;
  pidx [((size_t)b * 16 + strip) * N_PTS + j] = bi;
}

__global__ void argmax_cols_merge(
    const float* __restrict__ pbest, const int* __restrict__ pidx, int* __restrict__ nn21)
{
  int b = blockIdx.y;
  int j = blockIdx.x * 256 + threadIdx.x;
  float best = -1e30f; int bi = 0;
  for (int s = 0; s < 16; ++s) {
    float v = pbest[((size_t)b * 16 + s) * N_PTS + j];
    int ii = pidx[((size_t)b * 16 + s) * N_PTS + j];
    if (v > best) { best = v; bi = ii; }
  }
  nn21[b * N_PTS + j] = bi;
}

// ---------------- MLP + x0/x1 (point x neuron parallel, 2048 blocks) ----
__device__ __forceinline__ void inv3(const float* a, float* o) {
  float d = a[0]*(a[4]*a[8]-a[5]*a[7]) - a[1]*(a[3]*a[8]-a[5]*a[6]) + a[2]*(a[3]*a[7]-a[4]*a[6]);
  float id = 1.0f / d;
  o[0]=(a[4]*a[8]-a[5]*a[7])*id; o[1]=(a[2]*a[7]-a[1]*a[8])*id; o[2]=(a[1]*a[5]-a[2]*a[4])*id;
  o[3]=(a[5]*a[6]-a[3]*a[8])*id; o[4]=(a[0]*a[8]-a[2]*a[6])*id; o[5]=(a[2]*a[3]-a[0]*a[5])*id;
  o[6]=(a[3]*a[7]-a[4]*a[6])*id; o[7]=(a[1]*a[6]-a[0]*a[7])*id; o[8]=(a[0]*a[4]-a[1]*a[3])*id;
}

__global__ __launch_bounds__(256) void mlp_kernel(
    const float* __restrict__ feats, const float* __restrict__ scores,
    const float* __restrict__ kpts, const float* __restrict__ Kmat,
    const float* __restrict__ ms, const float* __restrict__ u, const float* __restrict__ v,
    const int* __restrict__ nn12, const int* __restrict__ nn21,
    const float* __restrict__ W1, const float* __restrict__ b1,
    const float* __restrict__ W2, const float* __restrict__ b2,
    const float* __restrict__ W3, const float* __restrict__ b3,
    float* __restrict__ conf, float* __restrict__ x0a, float* __restrict__ x1a)
{
  __shared__ float sW1T[131*66];   // [c][o], stride 66
  __shared__ float sW2T[64*66];    // [c][o], stride 66
  __shared__ float sx[4][132];     // per-point inputs
  __shared__ float sh[4][64];      // h exchange
  int t = threadIdx.x, b = blockIdx.y;
  int p = t >> 6;                  // 0..3
  int o = t & 63;                  // 0..63
  int n = blockIdx.x * 4 + p;

  for (int i = t; i < 64*131; i += 256) { int oo = i / 131, c = i - oo * 131; sW1T[c*66 + oo] = W1[i]; }
  for (int i = t; i < 64*64;  i += 256) { int oo = i >> 6, c = i & 63; sW2T[c*66 + oo] = W2[i]; }

  int nn = nn21[b * N_PTS + n];
  bool mutual = (nn12[b * N_PTS + nn] == n);
  int m = mutual ? nn : 0;
  float vf = mutual ? 1.0f : 0.0f;
  const float* f0r = feats + ((size_t)(2*b) * N_PTS + n) * 64;
  const float* f1r = feats + ((size_t)(2*b+1) * N_PTS + m) * 64;
  sx[p][o]      = f0r[o];
  sx[p][64 + o] = vf * f1r[o];
  if (o == 0) {
    sx[p][128] = scores[(size_t)(2*b) * N_PTS + n];
    sx[p][129] = vf * scores[(size_t)(2*b+1) * N_PTS + m];
    sx[p][130] = vf * (ms[((size_t)b * N_PTS + n) * N_PTS + m] + u[b*YSTR + n] + v[b*YSTR + m] - NORM_C);
  }
  __syncthreads();

  float h = b1[o];
  for (int c = 0; c < 131; ++c) h = fmaf(sW1T[c*66 + o], sx[p][c], h);
  sh[p][o] = fmaxf(h, 0.0f);
  __syncthreads();

  float h2 = b2[o];
  for (int c = 0; c < 64; ++c) h2 = fmaf(sW2T[c*66 + o], sh[p][c], h2);
  __syncthreads();
  sh[p][o] = fmaxf(h2, 0.0f);
  __syncthreads();

  if (o == 0) {
    float z = b3[0];
    for (int c = 0; c < 64; ++c) z = fmaf(W3[c], sh[p][c], z);
    conf[b * N_PTS + n] = vf / (1.0f + expf(-z));
  }

  if (o < 3) {
    float K0[9], K1[9], K0i[9], K1i[9];
    #pragma unroll
    for (int i = 0; i < 9; ++i) { K0[i] = Kmat[(size_t)(b*2+0)*9 + i]; K1[i] = Kmat[(size_t)(b*2+1)*9 + i]; }
    inv3(K0, K0i); inv3(K1, K1i);
    float kx0 = kpts[((size_t)(2*b) * N_PTS + n)*2 + 0], ky0 = kpts[((size_t)(2*b) * N_PTS + n)*2 + 1];
    float kx1 = vf * kpts[((size_t)(2*b+1) * N_PTS + m)*2 + 0], ky1 = vf * kpts[((size_t)(2*b+1) * N_PTS + m)*2 + 1];
    x0a[((size_t)b * N_PTS + n)*3 + o] = K0i[o*3+0]*kx0 + K0i[o*3+1]*ky0 + K0i[o*3+2];
    x1a[((size_t)b * N_PTS + n)*3 + o] = K1i[o*3+0]*kx1 + K1i[o*3+1]*ky1 + K1i[o*3+2];
  }
}

// ---------------- M9 accumulation ----------------
__global__ __launch_bounds__(256) void m9_kernel(
    const float* __restrict__ conf, const float* __restrict__ x0a, const float* __restrict__ x1a,
    float* __restrict__ M9)
{
  __shared__ float part[4][45];
  int b = blockIdx.x, t = threadIdx.x;
  int wv = t >> 6, l = t & 63;
  float acc[45];
  #pragma unroll
  for (int e = 0; e < 45; ++e) acc[e] = 0.0f;
  for (int n = t; n < N_PTS; n += 256) {
    float w = conf[b * N_PTS + n];
    float X0[3], X1[3];
    #pragma unroll
    for (int i = 0; i < 3; ++i) { X0[i] = x0a[((size_t)b*N_PTS+n)*3+i]; X1[i] = x1a[((size_t)b*N_PTS+n)*3+i]; }
    float a9[9];
    #pragma unroll
    for (int i = 0; i < 3; ++i)
      #pragma unroll
      for (int j = 0; j < 3; ++j) a9[3*i+j] = X1[i] * X0[j];
    int idx = 0;
    #pragma unroll
    for (int p = 0; p < 9; ++p)
      #pragma unroll
      for (int q = p; q < 9; ++q) { acc[idx] = fmaf(w * a9[p], a9[q], acc[idx]); ++idx; }
  }
  #pragma unroll
  for (int e = 0; e < 45; ++e) {
    float s = acc[e];
    for (int off = 32; off; off >>= 1) s += __shfl_down(s, off);
    if (l == 0) part[wv][e] = s;
  }
  __syncthreads();
  if (t < 45) M9[b*45 + t] = part[0][t] + part[1][t] + part[2][t] + part[3][t];
}

// ---------------- pose: eigen (readlane + skip; 8 sweeps) ----------------
template<int NN>
__device__ void jacobi_reg(float* A, float* V, int sweeps) {
  #pragma unroll
  for (int i = 0; i < NN*NN; ++i) V[i] = 0.0f;
  #pragma unroll
  for (int i = 0; i < NN; ++i) V[i*NN+i] = 1.0f;
  for (int s = 0; s < sweeps; ++s) {
    #pragma unroll
    for (int p = 0; p < NN-1; ++p) {
      #pragma unroll
      for (int q = p+1; q < NN; ++q) {
        float apq = A[p*NN+q];
        if (fabsf(apq) > 1e-30f) {
          float app = A[p*NN+p], aqq = A[q*NN+q];
          float tau = (aqq - app) / (2.0f * apq);
          float tt = (tau >= 0.0f ? 1.0f : -1.0f) / (fabsf(tau) + sqrtf(1.0f + tau*tau));
          float c = 1.0f / sqrtf(1.0f + tt*tt);
          float sn = tt * c;
          #pragma unroll
          for (int k = 0; k < NN; ++k) {
            float akp = A[k*NN+p], akq = A[k*NN+q];
            A[k*NN+p] = c*akp - sn*akq;
            A[k*NN+q] = sn*akp + c*akq;
          }
          #pragma unroll
          for (int k = 0; k < NN; ++k) {
            float apk = A[p*NN+k], aqk = A[q*NN+k];
            A[p*NN+k] = c*apk - sn*aqk;
            A[q*NN+k] = sn*apk + c*aqk;
          }
          #pragma unroll
          for (int k = 0; k < NN; ++k) {
            float vkp = V[k*NN+p], vkq = V[k*NN+q];
            V[k*NN+p] = c*vkp - sn*vkq;
            V[k*NN+q] = sn*vkp + c*vkq;
          }
        }
      }
    }
  }
}

__device__ __forceinline__ void cross3(const float* a, const float* b, float* o) {
  o[0] = a[1]*b[2] - a[2]*b[1];
  o[1] = a[2]*b[0] - a[0]*b[2];
  o[2] = a[0]*b[1] - a[1]*b[0];
}
__device__ __forceinline__ float dot3(const float* a, const float* b) {
  return a[0]*b[0] + a[1]*b[1] + a[2]*b[2];
}

__global__ __launch_bounds__(64, 1) void eigen_kernel(
    const float* __restrict__ M9, float* __restrict__ cndg)
{
  int b = blockIdx.x;
  int l = threadIdx.x;
  float Ar[9], Vr[9];
  #pragma unroll
  for (int c = 0; c < 9; ++c) { Ar[c] = 0.0f; Vr[c] = 0.0f; }
  if (l < 9) {
    #pragma unroll
    for (int c = 0; c < 9; ++c) {
      int p = l < c ? l : c, q = l < c ? c : l;
      int idx = p * 9 - (p * (p - 1)) / 2 + (q - p);
      Ar[c] = M9[b * 45 + idx];
    }
    #pragma unroll
    for (int c = 0; c < 9; ++c) Vr[c] = (c == l) ? 1.0f : 0.0f;
  }

  for (int s = 0; s < 8; ++s) {
    #pragma unroll
    for (int p = 0; p < 8; ++p) {
      #pragma unroll
      for (int q = p + 1; q < 9; ++q) {
        float app = RL(Ar[p], p);
        float apq = RL(Ar[q], p);
        float aqq = RL(Ar[q], q);
        float thr = 3e-7f * (fabsf(app) + fabsf(aqq));
        if (fabsf(apq) > 1e-30f && fabsf(apq) > thr) {   // uniform branch
          float gp[9], gq[9];
          #pragma unroll
          for (int k = 0; k < 9; ++k) { gp[k] = RL(Ar[k], p); gq[k] = RL(Ar[k], q); }
          float tau = (aqq - app) / (2.0f * apq);
          float tt = (tau >= 0.0f ? 1.0f : -1.0f) / (fabsf(tau) + sqrtf(1.0f + tau*tau));
          float cc = 1.0f / sqrtf(1.0f + tt*tt);
          float sn = tt * cc;
          float akp = Ar[p], akq = Ar[q];
          Ar[p] = cc*akp - sn*akq;
          Ar[q] = sn*akp + cc*akq;
          float pp = RL(Ar[p], p), pq = RL(Ar[q], p);
          float qp = RL(Ar[p], q), qq = RL(Ar[q], q);
          if (l == p) {
            #pragma unroll
            for (int k = 0; k < 9; ++k) {
              float rp_ = (k==p) ? pp : ((k==q) ? pq : gp[k]);
              float rq_ = (k==p) ? qp : ((k==q) ? qq : gq[k]);
              Ar[k] = cc*rp_ - sn*rq_;
            }
          } else if (l == q) {
            #pragma unroll
            for (int k = 0; k < 9; ++k) {
              float rp_ = (k==p) ? pp : ((k==q) ? pq : gp[k]);
              float rq_ = (k==p) ? qp : ((k==q) ? qq : gq[k]);
              Ar[k] = sn*rp_ + cc*rq_;
            }
          }
          float vkp = Vr[p], vkq = Vr[q];
          Vr[p] = cc*vkp - sn*vkq;
          Vr[q] = sn*vkp + cc*vkq;
        }
      }
    }
  }

  float dl = Ar[0];
  #pragma unroll
  for (int i = 1; i < 9; ++i) dl = (l == i) ? Ar[i] : dl;
  int mi = 0;
  float mv = RL(dl, 0);
  #pragma unroll
  for (int i = 1; i < 9; ++i) {
    float d = RL(dl, i);
    if (d < mv) { mv = d; mi = i; }
  }
  float vmi = Vr[0];
  #pragma unroll
  for (int i = 1; i < 9; ++i) vmi = (i == mi) ? Vr[i] : vmi;
  float Em[9];
  #pragma unroll
  for (int k = 0; k < 9; ++k) Em[k] = __shfl(vmi, k);

  if (l != 0) return;

  float B3[9], V3[9];
  #pragma unroll
  for (int i = 0; i < 3; ++i)
    #pragma unroll
    for (int j = 0; j < 3; ++j) {
      float s = 0.0f;
      #pragma unroll
      for (int r = 0; r < 3; ++r) s += Em[3*r+i] * Em[3*r+j];
      B3[i*3+j] = s;
    }
  jacobi_reg<3>(B3, V3, 10);
  float l0 = B3[0], l1 = B3[4], l2 = B3[8];
  float va[3] = {V3[0], V3[3], V3[6]};
  float vb[3] = {V3[1], V3[4], V3[7]};
  float vc[3] = {V3[2], V3[5], V3[8]};
  #define SWF(x,y) { float _t = x; x = y; y = _t; }
  #define SW3(x,y) { SWF(x[0],y[0]) SWF(x[1],y[1]) SWF(x[2],y[2]) }
  if (l0 < l1) { SWF(l0,l1) SW3(va,vb) }
  if (l0 < l2) { SWF(l0,l2) SW3(va,vc) }
  if (l1 < l2) { SWF(l1,l2) SW3(vb,vc) }
  float s0 = sqrtf(fmaxf(l0, 0.0f)) + 1e-20f;
  float s1 = sqrtf(fmaxf(l1, 0.0f)) + 1e-20f;
  float u0[3], u1[3], u2[3], Ev2[3];
  #pragma unroll
  for (int r = 0; r < 3; ++r) {
    u0[r]  = (Em[3*r]*va[0] + Em[3*r+1]*va[1] + Em[3*r+2]*va[2]) / s0;
    u1[r]  = (Em[3*r]*vb[0] + Em[3*r+1]*vb[1] + Em[3*r+2]*vb[2]) / s1;
    Ev2[r] =  Em[3*r]*vc[0] + Em[3*r+1]*vc[1] + Em[3*r+2]*vc[2];
  }
  cross3(u0, u1, u2);
  if (dot3(Ev2, u2) < 0.0f) { u2[0] = -u2[0]; u2[1] = -u2[1]; u2[2] = -u2[2]; }
  float c12[3]; cross3(u1, u2, c12);
  float detU = dot3(u0, c12);
  if (detU < 0.0f)
    #pragma unroll
    for (int i = 0; i < 3; ++i) { u0[i] = -u0[i]; u1[i] = -u1[i]; u2[i] = -u2[i]; }
  float cv[3]; cross3(vb, vc, cv);
  float detV = dot3(va, cv);
  if (detV < 0.0f)
    #pragma unroll
    for (int i = 0; i < 3; ++i) { va[i] = -va[i]; vb[i] = -vb[i]; vc[i] = -vc[i]; }
  float* C = cndg + b * 48;
  #pragma unroll
  for (int r = 0; r < 3; ++r)
    #pragma unroll
    for (int c = 0; c < 3; ++c) {
      float r1 =  u1[r]*va[c] - u0[r]*vb[c] + u2[r]*vc[c];
      float r2 = -u1[r]*va[c] + u0[r]*vb[c] + u2[r]*vc[c];
      C[0*12 + r*3+c] = r1; C[1*12 + r*3+c] = r1;
      C[2*12 + r*3+c] = r2; C[3*12 + r*3+c] = r2;
    }
  #pragma unroll
  for (int i = 0; i < 3; ++i) {
    C[0*12 + 9+i] = u2[i]; C[1*12 + 9+i] = -u2[i];
    C[2*12 + 9+i] = u2[i]; C[3*12 + 9+i] = -u2[i];
  }
}

// ---------------- pose: cheirality + output ----------------
__global__ __launch_bounds__(256) void cheir_kernel(
    const float* __restrict__ cndg, const float* __restrict__ conf,
    const float* __restrict__ x0a, const float* __restrict__ x1a,
    const float* __restrict__ t_scale, float* __restrict__ out)
{
  __shared__ float cnd[4][12];
  __shared__ float spart[4][4];
  int b = blockIdx.x, t = threadIdx.x;
  if (t < 48) cnd[t / 12][t % 12] = cndg[b * 48 + t];
  __syncthreads();
  float ls[4] = {0,0,0,0};
  for (int n = t; n < N_PTS; n += 256) {
    float w = conf[b * N_PTS + n];
    float X0[3], X1[3];
    #pragma unroll
    for (int i = 0; i < 3; ++i) { X0[i] = x0a[((size_t)b*N_PTS+n)*3+i]; X1[i] = x1a[((size_t)b*N_PTS+n)*3+i]; }
    #pragma unroll
    for (int k = 0; k < 4; ++k) {
      float rx = cnd[k][0]*X0[0] + cnd[k][1]*X0[1] + cnd[k][2]*X0[2];
      float ry = cnd[k][3]*X0[0] + cnd[k][4]*X0[1] + cnd[k][5]*X0[2];
      float rz = cnd[k][6]*X0[0] + cnd[k][7]*X0[1] + cnd[k][8]*X0[2];
      float tx = cnd[k][9], ty = cnd[k][10], tz = cnd[k][11];
      float cx = X1[1]*rz - X1[2]*ry;
      float cy = X1[2]*rx - X1[0]*rz;
      float cz = X1[0]*ry - X1[1]*rx;
      float ctx = X1[1]*tz - X1[2]*ty;
      float cty = X1[2]*tx - X1[0]*tz;
      float ctz = X1[0]*ty - X1[1]*tx;
      float num = ctx*cx + cty*cy + ctz*cz;
      float den = cx*cx + cy*cy + cz*cz + 1e-9f;
      float d0 = -num / den;
      float d1 = d0 * rz + tz;
      if (d0 > 0.0f && d1 > 0.0f) ls[k] += w;
    }
  }
  int wv = t >> 6, l = t & 63;
  #pragma unroll
  for (int k = 0; k < 4; ++k) {
    float s = ls[k];
    for (int off = 32; off; off >>= 1) s += __shfl_down(s, off);
    if (l == 0) spart[wv][k] = s;
  }
  __syncthreads();
  if (t == 0) {
    float sc[4];
    #pragma unroll
    for (int k = 0; k < 4; ++k) sc[k] = spart[0][k] + spart[1][k] + spart[2][k] + spart[3][k];
    int best = 0;
    #pragma unroll
    for (int k = 1; k < 4; ++k) if (sc[k] > sc[best]) best = k;
    float R[9], tv[3];
    #pragma unroll
    for (int i = 0; i < 9; ++i) R[i] = cnd[best][i];
    #pragma unroll
    for (int i = 0; i < 3; ++i) tv[i] = cnd[best][9+i];
    float tn = sqrtf(tv[0]*tv[0] + tv[1]*tv[1] + tv[2]*tv[2]) + 1e-9f;
    float scl = t_scale[b] / tn;
    float tb[3] = {tv[0]*scl, tv[1]*scl, tv[2]*scl};
    float* o = out + b * 32;
    #pragma unroll
    for (int r = 0; r < 3; ++r) {
      o[r*4+0] = R[r*3+0]; o[r*4+1] = R[r*3+1]; o[r*4+2] = R[r*3+2]; o[r*4+3] = tb[r];
    }
    o[12] = 0; o[13] = 0; o[14] = 0; o[15] = 1;
    float* oi = o + 16;
    #pragma unroll
    for (int r = 0; r < 3; ++r) {
      oi[r*4+0] = R[0*3+r]; oi[r*4+1] = R[1*3+r]; oi[r*4+2] = R[2*3+r];
      oi[r*4+3] = -(R[0*3+r]*tb[0] + R[1*3+r]*tb[1] + R[2*3+r]*tb[2]);
    }
    oi[12] = 0; oi[13] = 0; oi[14] = 0; oi[15] = 1;
  }
}

// ---------------- host ----------------
extern "C" void kernel_launch(void* const* d_in, const int* in_sizes, int n_in,
                              void* d_out, int out_size, void* d_ws, size_t ws_size,
                              hipStream_t stream) {
  (void)in_sizes; (void)n_in; (void)out_size;
  const float* feats   = (const float*)d_in[0];
  const float* scores  = (const float*)d_in[1];
  const float* kpts    = (const float*)d_in[2];
  const float* t_scale = (const float*)d_in[3];
  const float* Kmat    = (const float*)d_in[4];
  const float* binp    = (const float*)d_in[6];
  const float* W1 = (const float*)d_in[7];
  const float* b1 = (const float*)d_in[8];
  const float* W2 = (const float*)d_in[9];
  const float* b2 = (const float*)d_in[10];
  const float* W3 = (const float*)d_in[11];
  const float* b3 = (const float*)d_in[12];
  float* out = (float*)d_out;

  const size_t NELEM = (size_t)4 * N_PTS * N_PTS;   // 16,777,216
  char* w = (char*)d_ws;
  float* ms = (float*)w;          w += NELEM * 4;
  u16*   E  = (u16*)w;            w += NELEM * 2;
  u16*   ET = (u16*)w;            w += NELEM * 2;
  float* Yu = (float*)w;          w += (size_t)4 * YSTR * 4;
  float* Yv = (float*)w;          w += (size_t)4 * YSTR * 4;
  float* uA = (float*)w;          w += (size_t)4 * YSTR * 4;
  float* vA = (float*)w;          w += (size_t)4 * YSTR * 4;
  int* nn12 = (int*)w;            w += (size_t)4 * N_PTS * 4;
  int* nn21 = (int*)w;            w += (size_t)4 * N_PTS * 4;
  float* conf = (float*)w;        w += (size_t)4 * N_PTS * 4;
  float* x0a  = (float*)w;        w += (size_t)4 * N_PTS * 3 * 4;
  float* x1a  = (float*)w;        w += (size_t)4 * N_PTS * 3 * 4;
  float* M9   = (float*)w;        w += (size_t)4 * 45 * 4;
  float* cndg = (float*)w;        w += (size_t)4 * 48 * 4;
  float* pbest = (float*)w;       w += (size_t)4 * 16 * N_PTS * 4;
  int*   pidx  = (int*)w;         w += (size_t)4 * 16 * N_PTS * 4;
  if ((size_t)(w - (char*)d_ws) > ws_size) return;

  gemm_exp<<<dim3(32,32,4), 256, 0, stream>>>(feats, ms, E, ET, Yv);
  for (int it = 0; it < SINK_ITERS; ++it) {
    sink_half<<<dim3(128,4), 512, 0, stream>>>(E,  Yv, Yu, binp, 2048.0f);
    sink_half<<<dim3(128,4), 512, 0, stream>>>(ET, Yu, Yv, binp, 2048.0f);
  }
  uv_kernel<<<dim3(9,4), 256, 0, stream>>>(Yu, Yv, uA, vA);
  argmax_rows<<<dim3(512,4), 256, 0, stream>>>(ms, vA, nn12);
  argmax_cols_part<<<dim3(128,4), 256, 0, stream>>>(ms, uA, pbest, pidx);
  argmax_cols_merge<<<dim3(8,4), 256, 0, stream>>>(pbest, pidx, nn21);
  mlp_kernel<<<dim3(512,4), 256, 0, stream>>>(feats, scores, kpts, Kmat, ms, uA, vA,
                                              nn12, nn21, W1, b1, W2, b2, W3, b3,
                                              conf, x0a, x1a);
  m9_kernel<<<4, 256, 0, stream>>>(conf, x0a, x1a, M9);
  eigen_kernel<<<4, 64, 0, stream>>>(M9, cndg);
  cheir_kernel<<<4, 256, 0, stream>>>(cndg, conf, x0a, x1a, t_scale, out);
}

// Round 17
// 341.242 us; speedup vs baseline: 1.1650x; 1.0119x over previous
//
#include <hip/hip_runtime.h>
#include <hip/hip_fp16.h>

#define N_PTS 2048
#define YSTR 2052
#define SINK_ITERS 8
static constexpr float NORM_C = -8.31776616671934f; // -log(4096)

typedef unsigned short u16;
typedef unsigned int u32;

__device__ __forceinline__ float2 h2f2(u32 uu) {
  union { u32 u; __half2 h; } x; x.u = uu;
  return __half22float2(x.h);
}
__device__ __forceinline__ u16 f2h(float f) {
  __half h = __float2half_rn(f);
  return *(u16*)&h;
}
__device__ __forceinline__ float RL(float x, int lane) {
  return __int_as_float(__builtin_amdgcn_readlane(__float_as_int(x), lane));
}

// ------ Fused GEMM: ms=A·B^T/8 (fp32), E=expm1(ms) (fp16), ET=E^T via LDS ------
// Ts stride 82 u16 (41 dwords, odd): transpose-write row-step 164B = 4 mod 32
// dwords -> tx lanes span 8 banks (2-way, ~free) vs stride-84's 4-way.
// Rows 4B-aligned -> u32 reads.
__global__ __launch_bounds__(256) void gemm_exp(
    const float* __restrict__ feats,
    float* __restrict__ msOut, u16* __restrict__ E, u16* __restrict__ ET,
    float* __restrict__ Yv)
{
  __shared__ float As[64][65];
  __shared__ float Bs[64][65];
  __shared__ u16 Ts[64][82];
  int b = blockIdx.z;
  int i0 = blockIdx.x * 64, j0 = blockIdx.y * 64;
  int t = threadIdx.x;
  if (blockIdx.x == 0 && blockIdx.y == 0) {
    for (int i = t; i < N_PTS + 1; i += 256) Yv[b * YSTR + i] = 1.0f;
  }
  const float* Abase = feats + ((size_t)(2*b + 0) * N_PTS + i0) * 64;
  const float* Bbase = feats + ((size_t)(2*b + 1) * N_PTS + j0) * 64;
  for (int idx = t; idx < 4096; idx += 256) {
    int r = idx >> 6, c = idx & 63;
    As[r][c] = Abase[(size_t)r * 64 + c];
    Bs[r][c] = Bbase[(size_t)r * 64 + c];
  }
  __syncthreads();
  int tx = t & 15, ty = t >> 4;
  float acc[4][4] = {};
  for (int k = 0; k < 64; ++k) {
    float av[4], bv[4];
    #pragma unroll
    for (int d = 0; d < 4; ++d) { av[d] = As[ty*4+d][k]; bv[d] = Bs[tx*4+d][k]; }
    #pragma unroll
    for (int di = 0; di < 4; ++di)
      #pragma unroll
      for (int dj = 0; dj < 4; ++dj)
        acc[di][dj] = fmaf(av[di], bv[dj], acc[di][dj]);
  }
  #pragma unroll
  for (int di = 0; di < 4; ++di) {
    float4 m4; ushort4 e4;
    #pragma unroll
    for (int dj = 0; dj < 4; ++dj) {
      float val = acc[di][dj] * 0.125f;
      ((float*)&m4)[dj] = val;
      u16 eh = f2h(expm1f(val));
      ((u16*)&e4)[dj] = eh;
      Ts[tx*4+dj][ty*4+di] = eh;
    }
    size_t o = ((size_t)b * N_PTS + (i0 + ty*4 + di)) * N_PTS + (j0 + tx*4);
    *(float4*)(msOut + o) = m4;
    *(ushort4*)(E + o) = e4;
  }
  __syncthreads();
  for (int idx = t; idx < 2048; idx += 256) {
    int r = idx >> 5, seg = idx & 31;
    u32 w = *(const u32*)&Ts[r][seg*2];
    *(u32*)(ET + ((size_t)b * N_PTS + (j0 + r)) * N_PTS + i0 + seg*2) = w;
  }
}

// ---------------- Sinkhorn (proven: 2 rows/wave, grid 128x4) --------
__global__ __launch_bounds__(512) void sink_half(
    const u16* __restrict__ M, const float* __restrict__ Yin, float* __restrict__ Yout,
    const float* __restrict__ binp, float dustnum)
{
  int g = blockIdx.x;        // 0..127, 16 rows each
  int b = blockIdx.y;        // 0..3
  int t = threadIdx.x;
  int wv = t >> 6, l = t & 63;
  const float A = expf(binp[0]);
  const u16* Mb = M + (size_t)b * N_PTS * N_PTS;
  const float* Yi = Yin + b * YSTR;
  float* Yo = Yout + b * YSTR;
  float ybin = Yi[N_PTS];

  float yv[32];
  const float4* yp = (const float4*)(Yi + l * 32);
  #pragma unroll
  for (int k = 0; k < 8; ++k) {
    float4 f4 = yp[k];
    yv[k*4+0] = f4.x; yv[k*4+1] = f4.y; yv[k*4+2] = f4.z; yv[k*4+3] = f4.w;
  }

  int row0 = g * 16 + wv * 2;
  uint4 qv[2][4];
  #pragma unroll
  for (int r = 0; r < 2; ++r) {
    const uint4* rp = (const uint4*)(Mb + (size_t)(row0 + r) * N_PTS + l * 32);
    #pragma unroll
    for (int k = 0; k < 4; ++k) qv[r][k] = rp[k];
  }

  float Sv = 0.0f;
  #pragma unroll
  for (int k = 0; k < 32; ++k) Sv += yv[k];
  #pragma unroll
  for (int off = 32; off; off >>= 1) Sv += __shfl_xor(Sv, off);

  float acc[2];
  #pragma unroll
  for (int r = 0; r < 2; ++r) {
    float a = 0.0f;
    #pragma unroll
    for (int k = 0; k < 4; ++k) {
      uint4 q = qv[r][k];
      float2 f;
      f = h2f2(q.x); a = fmaf(f.x, yv[k*8+0], a); a = fmaf(f.y, yv[k*8+1], a);
      f = h2f2(q.y); a = fmaf(f.x, yv[k*8+2], a); a = fmaf(f.y, yv[k*8+3], a);
      f = h2f2(q.z); a = fmaf(f.x, yv[k*8+4], a); a = fmaf(f.y, yv[k*8+5], a);
      f = h2f2(q.w); a = fmaf(f.x, yv[k*8+6], a); a = fmaf(f.y, yv[k*8+7], a);
    }
    acc[r] = a;
  }
  #pragma unroll
  for (int r = 0; r < 2; ++r)
    #pragma unroll
    for (int off = 32; off; off >>= 1) acc[r] += __shfl_xor(acc[r], off);

  if (l == 0) {
    #pragma unroll
    for (int r = 0; r < 2; ++r)
      Yo[row0 + r] = 1.0f / (acc[r] + Sv + A * ybin);
  }
  if (g == 0 && t == 0)
    Yo[N_PTS] = dustnum / (A * (Sv + ybin));
}

__global__ void uv_kernel(const float* __restrict__ Yu, const float* __restrict__ Yv,
                          float* __restrict__ u, float* __restrict__ v) {
  int i = blockIdx.x * 256 + threadIdx.x;
  int b = blockIdx.y;
  if (i < N_PTS + 1) {
    u[b*YSTR + i] = NORM_C + logf(Yu[b*YSTR + i]);
    v[b*YSTR + i] = logf(Yv[b*YSTR + i]);
  }
}

// ------- fused matching: blocks 0..511 = row argmax, 512..639 = col strips ---
// Bodies byte-identical to the previous separate kernels -> bit-exact.
__global__ __launch_bounds__(256) void match_kernel(
    const float* __restrict__ ms, const float* __restrict__ u, const float* __restrict__ v,
    int* __restrict__ nn12, float* __restrict__ pbest, int* __restrict__ pidx)
{
  int b = blockIdx.y, t = threadIdx.x;
  if (blockIdx.x < 512) {
    int wv = t >> 6, l = t & 63;
    int row = blockIdx.x * 4 + wv;
    const float* vb = v + b * YSTR;
    float vv[32];
    const float4* vp = (const float4*)(vb + l * 32);
    #pragma unroll
    for (int k = 0; k < 8; ++k) {
      float4 f4 = vp[k];
      vv[k*4+0] = f4.x; vv[k*4+1] = f4.y; vv[k*4+2] = f4.z; vv[k*4+3] = f4.w;
    }
    const float4* rp4 = (const float4*)(ms + ((size_t)b * N_PTS + row) * N_PTS + l * 32);
    float best = -1e30f; int bj = 0;
    #pragma unroll
    for (int k = 0; k < 8; ++k) {
      float4 q = rp4[k];
      #pragma unroll
      for (int e = 0; e < 4; ++e) {
        float val = ((const float*)&q)[e] + vv[k*4 + e];
        int j = l*32 + k*4 + e;
        if (val > best) { best = val; bj = j; }
      }
    }
    for (int off = 32; off; off >>= 1) {
      float ov = __shfl_down(best, off);
      int oj = __shfl_down(bj, off);
      if (ov > best || (ov == best && oj < bj)) { best = ov; bj = oj; }
    }
    if (l == 0) nn12[b * N_PTS + row] = bj;
  } else {
    int bx = blockIdx.x - 512;        // 0..127
    int strip = bx >> 3;              // 0..15
    int jb = bx & 7;                  // 0..7
    int j = jb * 256 + t;
    const float* mb = ms + (size_t)b * N_PTS * N_PTS;
    const float* ub = u + b * YSTR;
    float best = -1e30f; int bi = 0;
    int i0 = strip * 128;
    for (int i = i0; i < i0 + 128; ++i) {
      float val = mb[(size_t)i * N_PTS + j] + ub[i];
      if (val > best) { best = val; bi = i; }
    }
    pbest[((size_t)b * 16 + strip) * N_PTS + j] = best;
    pidx [((size_t)b * 16 + strip) * N_PTS + j] = bi;
  }
}

__global__ void argmax_cols_merge(
    const float* __restrict__ pbest, const int* __restrict__ pidx, int* __restrict__ nn21)
{
  int b = blockIdx.y;
  int j = blockIdx.x * 256 + threadIdx.x;
  float best = -1e30f; int bi = 0;
  for (int s = 0; s < 16; ++s) {
    float v = pbest[((size_t)b * 16 + s) * N_PTS + j];
    int ii = pidx[((size_t)b * 16 + s) * N_PTS + j];
    if (v > best) { best = v; bi = ii; }
  }
  nn21[b * N_PTS + j] = bi;
}

// ---------------- MLP + x0/x1 (point x neuron parallel, 2048 blocks) ----
__device__ __forceinline__ void inv3(const float* a, float* o) {
  float d = a[0]*(a[4]*a[8]-a[5]*a[7]) - a[1]*(a[3]*a[8]-a[5]*a[6]) + a[2]*(a[3]*a[7]-a[4]*a[6]);
  float id = 1.0f / d;
  o[0]=(a[4]*a[8]-a[5]*a[7])*id; o[1]=(a[2]*a[7]-a[1]*a[8])*id; o[2]=(a[1]*a[5]-a[2]*a[4])*id;
  o[3]=(a[5]*a[6]-a[3]*a[8])*id; o[4]=(a[0]*a[8]-a[2]*a[6])*id; o[5]=(a[2]*a[3]-a[0]*a[5])*id;
  o[6]=(a[3]*a[7]-a[4]*a[6])*id; o[7]=(a[1]*a[6]-a[0]*a[7])*id; o[8]=(a[0]*a[4]-a[1]*a[3])*id;
}

__global__ __launch_bounds__(256) void mlp_kernel(
    const float* __restrict__ feats, const float* __restrict__ scores,
    const float* __restrict__ kpts, const float* __restrict__ Kmat,
    const float* __restrict__ ms, const float* __restrict__ u, const float* __restrict__ v,
    const int* __restrict__ nn12, const int* __restrict__ nn21,
    const float* __restrict__ W1, const float* __restrict__ b1,
    const float* __restrict__ W2, const float* __restrict__ b2,
    const float* __restrict__ W3, const float* __restrict__ b3,
    float* __restrict__ conf, float* __restrict__ x0a, float* __restrict__ x1a)
{
  __shared__ float sW1T[131*66];   // [c][o], stride 66
  __shared__ float sW2T[64*66];    // [c][o], stride 66
  __shared__ float sx[4][132];     // per-point inputs
  __shared__ float sh[4][64];      // h exchange
  int t = threadIdx.x, b = blockIdx.y;
  int p = t >> 6;                  // 0..3
  int o = t & 63;                  // 0..63
  int n = blockIdx.x * 4 + p;

  for (int i = t; i < 64*131; i += 256) { int oo = i / 131, c = i - oo * 131; sW1T[c*66 + oo] = W1[i]; }
  for (int i = t; i < 64*64;  i += 256) { int oo = i >> 6, c = i & 63; sW2T[c*66 + oo] = W2[i]; }

  int nn = nn21[b * N_PTS + n];
  bool mutual = (nn12[b * N_PTS + nn] == n);
  int m = mutual ? nn : 0;
  float vf = mutual ? 1.0f : 0.0f;
  const float* f0r = feats + ((size_t)(2*b) * N_PTS + n) * 64;
  const float* f1r = feats + ((size_t)(2*b+1) * N_PTS + m) * 64;
  sx[p][o]      = f0r[o];
  sx[p][64 + o] = vf * f1r[o];
  if (o == 0) {
    sx[p][128] = scores[(size_t)(2*b) * N_PTS + n];
    sx[p][129] = vf * scores[(size_t)(2*b+1) * N_PTS + m];
    sx[p][130] = vf * (ms[((size_t)b * N_PTS + n) * N_PTS + m] + u[b*YSTR + n] + v[b*YSTR + m] - NORM_C);
  }
  __syncthreads();

  float h = b1[o];
  for (int c = 0; c < 131; ++c) h = fmaf(sW1T[c*66 + o], sx[p][c], h);
  sh[p][o] = fmaxf(h, 0.0f);
  __syncthreads();

  float h2 = b2[o];
  for (int c = 0; c < 64; ++c) h2 = fmaf(sW2T[c*66 + o], sh[p][c], h2);
  __syncthreads();
  sh[p][o] = fmaxf(h2, 0.0f);
  __syncthreads();

  if (o == 0) {
    float z = b3[0];
    for (int c = 0; c < 64; ++c) z = fmaf(W3[c], sh[p][c], z);
    conf[b * N_PTS + n] = vf / (1.0f + expf(-z));
  }

  if (o < 3) {
    float K0[9], K1[9], K0i[9], K1i[9];
    #pragma unroll
    for (int i = 0; i < 9; ++i) { K0[i] = Kmat[(size_t)(b*2+0)*9 + i]; K1[i] = Kmat[(size_t)(b*2+1)*9 + i]; }
    inv3(K0, K0i); inv3(K1, K1i);
    float kx0 = kpts[((size_t)(2*b) * N_PTS + n)*2 + 0], ky0 = kpts[((size_t)(2*b) * N_PTS + n)*2 + 1];
    float kx1 = vf * kpts[((size_t)(2*b+1) * N_PTS + m)*2 + 0], ky1 = vf * kpts[((size_t)(2*b+1) * N_PTS + m)*2 + 1];
    x0a[((size_t)b * N_PTS + n)*3 + o] = K0i[o*3+0]*kx0 + K0i[o*3+1]*ky0 + K0i[o*3+2];
    x1a[((size_t)b * N_PTS + n)*3 + o] = K1i[o*3+0]*kx1 + K1i[o*3+1]*ky1 + K1i[o*3+2];
  }
}

// ---------------- M9 accumulation ----------------
__global__ __launch_bounds__(256) void m9_kernel(
    const float* __restrict__ conf, const float* __restrict__ x0a, const float* __restrict__ x1a,
    float* __restrict__ M9)
{
  __shared__ float part[4][45];
  int b = blockIdx.x, t = threadIdx.x;
  int wv = t >> 6, l = t & 63;
  float acc[45];
  #pragma unroll
  for (int e = 0; e < 45; ++e) acc[e] = 0.0f;
  for (int n = t; n < N_PTS; n += 256) {
    float w = conf[b * N_PTS + n];
    float X0[3], X1[3];
    #pragma unroll
    for (int i = 0; i < 3; ++i) { X0[i] = x0a[((size_t)b*N_PTS+n)*3+i]; X1[i] = x1a[((size_t)b*N_PTS+n)*3+i]; }
    float a9[9];
    #pragma unroll
    for (int i = 0; i < 3; ++i)
      #pragma unroll
      for (int j = 0; j < 3; ++j) a9[3*i+j] = X1[i] * X0[j];
    int idx = 0;
    #pragma unroll
    for (int p = 0; p < 9; ++p)
      #pragma unroll
      for (int q = p; q < 9; ++q) { acc[idx] = fmaf(w * a9[p], a9[q], acc[idx]); ++idx; }
  }
  #pragma unroll
  for (int e = 0; e < 45; ++e) {
    float s = acc[e];
    for (int off = 32; off; off >>= 1) s += __shfl_down(s, off);
    if (l == 0) part[wv][e] = s;
  }
  __syncthreads();
  if (t < 45) M9[b*45 + t] = part[0][t] + part[1][t] + part[2][t] + part[3][t];
}

// ---------------- pose: eigen (readlane + skip; 6 sweeps) ----------------
// 6 sweeps (was 8): R10 (skip ~ no-skip at 12) and R12 (12->8) were both
// bit-identical => rotations after sweep ~6 are all below the relative skip
// threshold (Jacobi quadratic convergence: off-diag ~1e-12 rel by sweep 6).
template<int NN>
__device__ void jacobi_reg(float* A, float* V, int sweeps) {
  #pragma unroll
  for (int i = 0; i < NN*NN; ++i) V[i] = 0.0f;
  #pragma unroll
  for (int i = 0; i < NN; ++i) V[i*NN+i] = 1.0f;
  for (int s = 0; s < sweeps; ++s) {
    #pragma unroll
    for (int p = 0; p < NN-1; ++p) {
      #pragma unroll
      for (int q = p+1; q < NN; ++q) {
        float apq = A[p*NN+q];
        if (fabsf(apq) > 1e-30f) {
          float app = A[p*NN+p], aqq = A[q*NN+q];
          float tau = (aqq - app) / (2.0f * apq);
          float tt = (tau >= 0.0f ? 1.0f : -1.0f) / (fabsf(tau) + sqrtf(1.0f + tau*tau));
          float c = 1.0f / sqrtf(1.0f + tt*tt);
          float sn = tt * c;
          #pragma unroll
          for (int k = 0; k < NN; ++k) {
            float akp = A[k*NN+p], akq = A[k*NN+q];
            A[k*NN+p] = c*akp - sn*akq;
            A[k*NN+q] = sn*akp + c*akq;
          }
          #pragma unroll
          for (int k = 0; k < NN; ++k) {
            float apk = A[p*NN+k], aqk = A[q*NN+k];
            A[p*NN+k] = c*apk - sn*aqk;
            A[q*NN+k] = sn*apk + c*aqk;
          }
          #pragma unroll
          for (int k = 0; k < NN; ++k) {
            float vkp = V[k*NN+p], vkq = V[k*NN+q];
            V[k*NN+p] = c*vkp - sn*vkq;
            V[k*NN+q] = sn*vkp + c*vkq;
          }
        }
      }
    }
  }
}

__device__ __forceinline__ void cross3(const float* a, const float* b, float* o) {
  o[0] = a[1]*b[2] - a[2]*b[1];
  o[1] = a[2]*b[0] - a[0]*b[2];
  o[2] = a[0]*b[1] - a[1]*b[0];
}
__device__ __forceinline__ float dot3(const float* a, const float* b) {
  return a[0]*b[0] + a[1]*b[1] + a[2]*b[2];
}

__global__ __launch_bounds__(64, 1) void eigen_kernel(
    const float* __restrict__ M9, float* __restrict__ cndg)
{
  int b = blockIdx.x;
  int l = threadIdx.x;
  float Ar[9], Vr[9];
  #pragma unroll
  for (int c = 0; c < 9; ++c) { Ar[c] = 0.0f; Vr[c] = 0.0f; }
  if (l < 9) {
    #pragma unroll
    for (int c = 0; c < 9; ++c) {
      int p = l < c ? l : c, q = l < c ? c : l;
      int idx = p * 9 - (p * (p - 1)) / 2 + (q - p);
      Ar[c] = M9[b * 45 + idx];
    }
    #pragma unroll
    for (int c = 0; c < 9; ++c) Vr[c] = (c == l) ? 1.0f : 0.0f;
  }

  for (int s = 0; s < 6; ++s) {
    #pragma unroll
    for (int p = 0; p < 8; ++p) {
      #pragma unroll
      for (int q = p + 1; q < 9; ++q) {
        float app = RL(Ar[p], p);
        float apq = RL(Ar[q], p);
        float aqq = RL(Ar[q], q);
        float thr = 3e-7f * (fabsf(app) + fabsf(aqq));
        if (fabsf(apq) > 1e-30f && fabsf(apq) > thr) {   // uniform branch
          float gp[9], gq[9];
          #pragma unroll
          for (int k = 0; k < 9; ++k) { gp[k] = RL(Ar[k], p); gq[k] = RL(Ar[k], q); }
          float tau = (aqq - app) / (2.0f * apq);
          float tt = (tau >= 0.0f ? 1.0f : -1.0f) / (fabsf(tau) + sqrtf(1.0f + tau*tau));
          float cc = 1.0f / sqrtf(1.0f + tt*tt);
          float sn = tt * cc;
          float akp = Ar[p], akq = Ar[q];
          Ar[p] = cc*akp - sn*akq;
          Ar[q] = sn*akp + cc*akq;
          float pp = RL(Ar[p], p), pq = RL(Ar[q], p);
          float qp = RL(Ar[p], q), qq = RL(Ar[q], q);
          if (l == p) {
            #pragma unroll
            for (int k = 0; k < 9; ++k) {
              float rp_ = (k==p) ? pp : ((k==q) ? pq : gp[k]);
              float rq_ = (k==p) ? qp : ((k==q) ? qq : gq[k]);
              Ar[k] = cc*rp_ - sn*rq_;
            }
          } else if (l == q) {
            #pragma unroll
            for (int k = 0; k < 9; ++k) {
              float rp_ = (k==p) ? pp : ((k==q) ? pq : gp[k]);
              float rq_ = (k==p) ? qp : ((k==q) ? qq : gq[k]);
              Ar[k] = sn*rp_ + cc*rq_;
            }
          }
          float vkp = Vr[p], vkq = Vr[q];
          Vr[p] = cc*vkp - sn*vkq;
          Vr[q] = sn*vkp + cc*vkq;
        }
      }
    }
  }

  float dl = Ar[0];
  #pragma unroll
  for (int i = 1; i < 9; ++i) dl = (l == i) ? Ar[i] : dl;
  int mi = 0;
  float mv = RL(dl, 0);
  #pragma unroll
  for (int i = 1; i < 9; ++i) {
    float d = RL(dl, i);
    if (d < mv) { mv = d; mi = i; }
  }
  float vmi = Vr[0];
  #pragma unroll
  for (int i = 1; i < 9; ++i) vmi = (i == mi) ? Vr[i] : vmi;
  float Em[9];
  #pragma unroll
  for (int k = 0; k < 9; ++k) Em[k] = __shfl(vmi, k);

  if (l != 0) return;

  float B3[9], V3[9];
  #pragma unroll
  for (int i = 0; i < 3; ++i)
    #pragma unroll
    for (int j = 0; j < 3; ++j) {
      float s = 0.0f;
      #pragma unroll
      for (int r = 0; r < 3; ++r) s += Em[3*r+i] * Em[3*r+j];
      B3[i*3+j] = s;
    }
  jacobi_reg<3>(B3, V3, 10);
  float l0 = B3[0], l1 = B3[4], l2 = B3[8];
  float va[3] = {V3[0], V3[3], V3[6]};
  float vb[3] = {V3[1], V3[4], V3[7]};
  float vc[3] = {V3[2], V3[5], V3[8]};
  #define SWF(x,y) { float _t = x; x = y; y = _t; }
  #define SW3(x,y) { SWF(x[0],y[0]) SWF(x[1],y[1]) SWF(x[2],y[2]) }
  if (l0 < l1) { SWF(l0,l1) SW3(va,vb) }
  if (l0 < l2) { SWF(l0,l2) SW3(va,vc) }
  if (l1 < l2) { SWF(l1,l2) SW3(vb,vc) }
  float s0 = sqrtf(fmaxf(l0, 0.0f)) + 1e-20f;
  float s1 = sqrtf(fmaxf(l1, 0.0f)) + 1e-20f;
  float u0[3], u1[3], u2[3], Ev2[3];
  #pragma unroll
  for (int r = 0; r < 3; ++r) {
    u0[r]  = (Em[3*r]*va[0] + Em[3*r+1]*va[1] + Em[3*r+2]*va[2]) / s0;
    u1[r]  = (Em[3*r]*vb[0] + Em[3*r+1]*vb[1] + Em[3*r+2]*vb[2]) / s1;
    Ev2[r] =  Em[3*r]*vc[0] + Em[3*r+1]*vc[1] + Em[3*r+2]*vc[2];
  }
  cross3(u0, u1, u2);
  if (dot3(Ev2, u2) < 0.0f) { u2[0] = -u2[0]; u2[1] = -u2[1]; u2[2] = -u2[2]; }
  float c12[3]; cross3(u1, u2, c12);
  float detU = dot3(u0, c12);
  if (detU < 0.0f)
    #pragma unroll
    for (int i = 0; i < 3; ++i) { u0[i] = -u0[i]; u1[i] = -u1[i]; u2[i] = -u2[i]; }
  float cv[3]; cross3(vb, vc, cv);
  float detV = dot3(va, cv);
  if (detV < 0.0f)
    #pragma unroll
    for (int i = 0; i < 3; ++i) { va[i] = -va[i]; vb[i] = -vb[i]; vc[i] = -vc[i]; }
  float* C = cndg + b * 48;
  #pragma unroll
  for (int r = 0; r < 3; ++r)
    #pragma unroll
    for (int c = 0; c < 3; ++c) {
      float r1 =  u1[r]*va[c] - u0[r]*vb[c] + u2[r]*vc[c];
      float r2 = -u1[r]*va[c] + u0[r]*vb[c] + u2[r]*vc[c];
      C[0*12 + r*3+c] = r1; C[1*12 + r*3+c] = r1;
      C[2*12 + r*3+c] = r2; C[3*12 + r*3+c] = r2;
    }
  #pragma unroll
  for (int i = 0; i < 3; ++i) {
    C[0*12 + 9+i] = u2[i]; C[1*12 + 9+i] = -u2[i];
    C[2*12 + 9+i] = u2[i]; C[3*12 + 9+i] = -u2[i];
  }
}

// ---------------- pose: cheirality + output ----------------
__global__ __launch_bounds__(256) void cheir_kernel(
    const float* __restrict__ cndg, const float* __restrict__ conf,
    const float* __restrict__ x0a, const float* __restrict__ x1a,
    const float* __restrict__ t_scale, float* __restrict__ out)
{
  __shared__ float cnd[4][12];
  __shared__ float spart[4][4];
  int b = blockIdx.x, t = threadIdx.x;
  if (t < 48) cnd[t / 12][t % 12] = cndg[b * 48 + t];
  __syncthreads();
  float ls[4] = {0,0,0,0};
  for (int n = t; n < N_PTS; n += 256) {
    float w = conf[b * N_PTS + n];
    float X0[3], X1[3];
    #pragma unroll
    for (int i = 0; i < 3; ++i) { X0[i] = x0a[((size_t)b*N_PTS+n)*3+i]; X1[i] = x1a[((size_t)b*N_PTS+n)*3+i]; }
    #pragma unroll
    for (int k = 0; k < 4; ++k) {
      float rx = cnd[k][0]*X0[0] + cnd[k][1]*X0[1] + cnd[k][2]*X0[2];
      float ry = cnd[k][3]*X0[0] + cnd[k][4]*X0[1] + cnd[k][5]*X0[2];
      float rz = cnd[k][6]*X0[0] + cnd[k][7]*X0[1] + cnd[k][8]*X0[2];
      float tx = cnd[k][9], ty = cnd[k][10], tz = cnd[k][11];
      float cx = X1[1]*rz - X1[2]*ry;
      float cy = X1[2]*rx - X1[0]*rz;
      float cz = X1[0]*ry - X1[1]*rx;
      float ctx = X1[1]*tz - X1[2]*ty;
      float cty = X1[2]*tx - X1[0]*tz;
      float ctz = X1[0]*ty - X1[1]*tx;
      float num = ctx*cx + cty*cy + ctz*cz;
      float den = cx*cx + cy*cy + cz*cz + 1e-9f;
      float d0 = -num / den;
      float d1 = d0 * rz + tz;
      if (d0 > 0.0f && d1 > 0.0f) ls[k] += w;
    }
  }
  int wv = t >> 6, l = t & 63;
  #pragma unroll
  for (int k = 0; k < 4; ++k) {
    float s = ls[k];
    for (int off = 32; off; off >>= 1) s += __shfl_down(s, off);
    if (l == 0) spart[wv][k] = s;
  }
  __syncthreads();
  if (t == 0) {
    float sc[4];
    #pragma unroll
    for (int k = 0; k < 4; ++k) sc[k] = spart[0][k] + spart[1][k] + spart[2][k] + spart[3][k];
    int best = 0;
    #pragma unroll
    for (int k = 1; k < 4; ++k) if (sc[k] > sc[best]) best = k;
    float R[9], tv[3];
    #pragma unroll
    for (int i = 0; i < 9; ++i) R[i] = cnd[best][i];
    #pragma unroll
    for (int i = 0; i < 3; ++i) tv[i] = cnd[best][9+i];
    float tn = sqrtf(tv[0]*tv[0] + tv[1]*tv[1] + tv[2]*tv[2]) + 1e-9f;
    float scl = t_scale[b] / tn;
    float tb[3] = {tv[0]*scl, tv[1]*scl, tv[2]*scl};
    float* o = out + b * 32;
    #pragma unroll
    for (int r = 0; r < 3; ++r) {
      o[r*4+0] = R[r*3+0]; o[r*4+1] = R[r*3+1]; o[r*4+2] = R[r*3+2]; o[r*4+3] = tb[r];
    }
    o[12] = 0; o[13] = 0; o[14] = 0; o[15] = 1;
    float* oi = o + 16;
    #pragma unroll
    for (int r = 0; r < 3; ++r) {
      oi[r*4+0] = R[0*3+r]; oi[r*4+1] = R[1*3+r]; oi[r*4+2] = R[2*3+r];
      oi[r*4+3] = -(R[0*3+r]*tb[0] + R[1*3+r]*tb[1] + R[2*3+r]*tb[2]);
    }
    oi[12] = 0; oi[13] = 0; oi[14] = 0; oi[15] = 1;
  }
}

// ---------------- host ----------------
extern "C" void kernel_launch(void* const* d_in, const int* in_sizes, int n_in,
                              void* d_out, int out_size, void* d_ws, size_t ws_size,
                              hipStream_t stream) {
  (void)in_sizes; (void)n_in; (void)out_size;
  const float* feats   = (const float*)d_in[0];
  const float* scores  = (const float*)d_in[1];
  const float* kpts    = (const float*)d_in[2];
  const float* t_scale = (const float*)d_in[3];
  const float* Kmat    = (const float*)d_in[4];
  const float* binp    = (const float*)d_in[6];
  const float* W1 = (const float*)d_in[7];
  const float* b1 = (const float*)d_in[8];
  const float* W2 = (const float*)d_in[9];
  const float* b2 = (const float*)d_in[10];
  const float* W3 = (const float*)d_in[11];
  const float* b3 = (const float*)d_in[12];
  float* out = (float*)d_out;

  const size_t NELEM = (size_t)4 * N_PTS * N_PTS;   // 16,777,216
  char* w = (char*)d_ws;
  float* ms = (float*)w;          w += NELEM * 4;
  u16*   E  = (u16*)w;            w += NELEM * 2;
  u16*   ET = (u16*)w;            w += NELEM * 2;
  float* Yu = (float*)w;          w += (size_t)4 * YSTR * 4;
  float* Yv = (float*)w;          w += (size_t)4 * YSTR * 4;
  float* uA = (float*)w;          w += (size_t)4 * YSTR * 4;
  float* vA = (float*)w;          w += (size_t)4 * YSTR * 4;
  int* nn12 = (int*)w;            w += (size_t)4 * N_PTS * 4;
  int* nn21 = (int*)w;            w += (size_t)4 * N_PTS * 4;
  float* conf = (float*)w;        w += (size_t)4 * N_PTS * 4;
  float* x0a  = (float*)w;        w += (size_t)4 * N_PTS * 3 * 4;
  float* x1a  = (float*)w;        w += (size_t)4 * N_PTS * 3 * 4;
  float* M9   = (float*)w;        w += (size_t)4 * 45 * 4;
  float* cndg = (float*)w;        w += (size_t)4 * 48 * 4;
  float* pbest = (float*)w;       w += (size_t)4 * 16 * N_PTS * 4;
  int*   pidx  = (int*)w;         w += (size_t)4 * 16 * N_PTS * 4;
  if ((size_t)(w - (char*)d_ws) > ws_size) return;

  gemm_exp<<<dim3(32,32,4), 256, 0, stream>>>(feats, ms, E, ET, Yv);
  for (int it = 0; it < SINK_ITERS; ++it) {
    sink_half<<<dim3(128,4), 512, 0, stream>>>(E,  Yv, Yu, binp, 2048.0f);
    sink_half<<<dim3(128,4), 512, 0, stream>>>(ET, Yu, Yv, binp, 2048.0f);
  }
  uv_kernel<<<dim3(9,4), 256, 0, stream>>>(Yu, Yv, uA, vA);
  match_kernel<<<dim3(640,4), 256, 0, stream>>>(ms, uA, vA, nn12, pbest, pidx);
  argmax_cols_merge<<<dim3(8,4), 256, 0, stream>>>(pbest, pidx, nn21);
  mlp_kernel<<<dim3(512,4), 256, 0, stream>>>(feats, scores, kpts, Kmat, ms, uA, vA,
                                              nn12, nn21, W1, b1, W2, b2, W3, b3,
                                              conf, x0a, x1a);
  m9_kernel<<<4, 256, 0, stream>>>(conf, x0a, x1a, M9);
  eigen_kernel<<<4, 64, 0, stream>>>(M9, cndg);
  cheir_kernel<<<4, 256, 0, stream>>>(cndg, conf, x0a, x1a, t_scale, out);
}